// Round 8
// baseline (87.284 us; speedup 1.0000x reference)
//
#include <hip/hip_runtime.h>

// Problem constants (fixed by setup_inputs)
constexpr int B     = 1000;
constexpr int T_PER = 250;
constexpr int M_PER = 50;
constexpr int N_T   = B * T_PER;   // 250000
constexpr int N_M   = B * M_PER;   // 50000
constexpr int H     = 128;
constexpr int N_LBL = 25000;
constexpr float EPS = 1e-05f;

constexpr int NB_T = 256;  // bn_stats blocks (tasks)
constexpr int NB_M = 64;   // bn_stats blocks (machines)
constexpr int NB_P = 64;   // prep blocks

// ---- ws layout ----
constexpr int OFF_PART_T = 0;                       // 256 blocks * 32
constexpr int OFF_PART_M = OFF_PART_T + NB_T * 32;  // 64 blocks * 16
constexpr int OFF_AT     = OFF_PART_M + NB_M * 16;  // 16
constexpr int OFF_BT     = OFF_AT + 16;
constexpr int OFF_AM     = OFF_BT + 16;
constexpr int OFF_BM     = OFF_AM + 8;
constexpr int OFF_BT1F   = OFF_BM + 8;              // 128 folded bt1
constexpr int OFF_BM1F   = OFF_BT1F + 128;          // 128 folded bm1
constexpr int OFF_MEANT  = OFF_BM1F + 128;          // B*H task means
constexpr int OFF_MEANM  = OFF_MEANT + B * H;       // B*H machine means
constexpr int OFF_AGG2   = OFF_MEANM + B * H;       // B*H aggr output (Wl1b-folded)
constexpr int OFF_BFOLD  = OFF_AGG2 + B * H;        // 128: bl2@Wo1 + bo1
constexpr int OFF_HALF   = OFF_BFOLD + 128;         // fp16 region (16B aligned)
// fp16 region (half offsets from wh)
constexpr int HO_WT1  = 0;       // 128*32 (prescaled + bias cols 16,17 — written by finalize)
constexpr int HO_WT2  = 4096;    // 128*128
constexpr int HO_WM1  = 20480;   // 128*32 (prescaled + bias cols 8,9)
constexpr int HO_WM2  = 24576;   // 128*128
constexpr int HO_WA1  = 40960;   // 128*256
constexpr int HO_WA2  = 73728;   // 128*128
constexpr int HO_WL1  = 90112;   // 128*384
constexpr int HO_WLO  = 139264;  // 128*128: (Wl2@Wo1) in WT layout — written by finalize
constexpr int HO_WO1  = 155648;  // 128*128 (consumed by finalize's fold)
constexpr int HO_XT16 = 172032;             // N_T*16 f16
constexpr int HO_XM16 = HO_XT16 + N_T * 16; // N_M*8 f16

typedef _Float16 f16x8 __attribute__((ext_vector_type(8)));
typedef _Float16 f16x4 __attribute__((ext_vector_type(4)));
typedef float f32x4 __attribute__((ext_vector_type(4)));

#define MFMA16(a, b, c) __builtin_amdgcn_mfma_f32_16x16x32_f16(a, b, c, 0, 0, 0)

// ---------------- column-split MFMA helpers ----------------
__device__ __forceinline__ void zacc(f32x4 acc[4][2]) {
#pragma unroll
    for (int rg = 0; rg < 4; rg++)
#pragma unroll
        for (int mi = 0; mi < 2; mi++) acc[rg][mi] = (f32x4){0.f, 0.f, 0.f, 0.f};
}

__device__ __forceinline__ void ld32(f16x8 w[2], const _Float16* __restrict__ WT,
                                     int m0, int r, int gq) {
#pragma unroll
    for (int mi = 0; mi < 2; mi++)
        w[mi] = *(const f16x8*)(WT + ((m0 + mi) * 16 + r) * 32 + gq * 8);
}

__device__ __forceinline__ void ld128(f16x8 w[2][4], const _Float16* __restrict__ WT,
                                      int lda, int k0, int m0, int r, int gq) {
#pragma unroll
    for (int mi = 0; mi < 2; mi++)
#pragma unroll
        for (int ks = 0; ks < 4; ks++)
            w[mi][ks] = *(const f16x8*)(WT + ((m0 + mi) * 16 + r) * lda + k0 + ks * 32 + gq * 8);
}

// GEMM1 with B-fragments in registers
__device__ __forceinline__ void mm32g(const f16x8 w[2], const f16x8 xb[4], f32x4 acc[4][2]) {
#pragma unroll
    for (int rg = 0; rg < 4; rg++) {
        acc[rg][0] = MFMA16(w[0], xb[rg], acc[rg][0]);
        acc[rg][1] = MFMA16(w[1], xb[rg], acc[rg][1]);
    }
}

__device__ __forceinline__ void mm32(const f16x8 w[2], const _Float16* __restrict__ act,
                                     int rstride, int r, int gq, f32x4 acc[4][2]) {
#pragma unroll
    for (int rg = 0; rg < 4; rg++) {
        const f16x8 bf = *(const f16x8*)(act + (rg * 16 + r) * rstride + gq * 8);
        acc[rg][0] = MFMA16(w[0], bf, acc[rg][0]);
        acc[rg][1] = MFMA16(w[1], bf, acc[rg][1]);
    }
}

__device__ __forceinline__ void mm128(const f16x8 w[2][4], const _Float16* __restrict__ act,
                                      int rstride, int r, int gq, f32x4 acc[4][2]) {
#pragma unroll
    for (int rg = 0; rg < 4; rg++)
#pragma unroll
        for (int ks = 0; ks < 4; ks++) {
            const f16x8 bf = *(const f16x8*)(act + (rg * 16 + r) * rstride + ks * 32 + gq * 8);
            acc[rg][0] = MFMA16(w[0][ks], bf, acc[rg][0]);
            acc[rg][1] = MFMA16(w[1][ks], bf, acc[rg][1]);
        }
}

__device__ __forceinline__ void epi_cs(const f32x4 acc[4][2], const f32x4 bv[2],
                                       _Float16* __restrict__ dst, int dstride,
                                       int m0, int r, int gq, bool relu) {
#pragma unroll
    for (int rg = 0; rg < 4; rg++)
#pragma unroll
        for (int mi = 0; mi < 2; mi++) {
            f16x4 hv;
#pragma unroll
            for (int j = 0; j < 4; j++) {
                float v = acc[rg][mi][j] + bv[mi][j];
                if (relu) v = fmaxf(v, 0.f);
                hv[j] = (_Float16)v;
            }
            *(f16x4*)(dst + (rg * 16 + r) * dstride + (m0 + mi) * 16 + gq * 4) = hv;
        }
}

// ---------------- K1: BN partial stats + x->f16 dump + weight transpose/convert ----------------
template <int C, int NB>
__device__ __forceinline__ void stats_body(const float* __restrict__ x,
                                           _Float16* __restrict__ x16, int nelem,
                                           float* __restrict__ part, int blk, int t,
                                           float* ls, float* lq) {
    float s = 0.f, q = 0.f;
    for (int e = blk * 256 + t; e < nelem; e += NB * 256) {
        float v = x[e];
        s += v;
        q += v * v;
        x16[e] = (_Float16)v;
    }
    ls[t] = s; lq[t] = q;
    __syncthreads();
    if (t < C) {
        float S = 0.f, Q = 0.f;
        for (int u = t; u < 256; u += C) { S += ls[u]; Q += lq[u]; }
        part[blk * 2 * C + t] = S;
        part[blk * 2 * C + C + t] = Q;
    }
}

__device__ __forceinline__ void cvt_tr(const float* __restrict__ src, _Float16* __restrict__ dst,
                                       int K, int Kp, int tid, int nt) {
    for (int idx = tid; idx < 128 * Kp; idx += nt) {
        int c = idx / Kp, k = idx - c * Kp;
        float v = (k < K) ? src[k * 128 + c] : 0.f;
        dst[idx] = (_Float16)v;
    }
}

__global__ __launch_bounds__(256) void stats_prep_kernel(
        const float* __restrict__ xt, const float* __restrict__ xm,
        _Float16* __restrict__ xt16, _Float16* __restrict__ xm16,
        const float* __restrict__ Wt2, const float* __restrict__ Wm2,
        const float* __restrict__ Wa1, const float* __restrict__ Wa2,
        const float* __restrict__ Wl1, const float* __restrict__ Wo1,
        float* __restrict__ wsf, _Float16* __restrict__ wh) {
    __shared__ float ls[256], lq[256];
    const int bid = blockIdx.x, t = threadIdx.x;
    if (bid < NB_T) {
        stats_body<16, NB_T>(xt, xt16, N_T * 16, wsf + OFF_PART_T, bid, t, ls, lq);
    } else if (bid < NB_T + NB_M) {
        stats_body<8, NB_M>(xm, xm16, N_M * 8, wsf + OFF_PART_M, bid - NB_T, t, ls, lq);
    } else {
        const int tid = (bid - NB_T - NB_M) * 256 + t;
        const int nt = NB_P * 256;
        cvt_tr(Wt2, wh + HO_WT2, 128, 128, tid, nt);
        cvt_tr(Wm2, wh + HO_WM2, 128, 128, tid, nt);
        cvt_tr(Wa1, wh + HO_WA1, 256, 256, tid, nt);
        cvt_tr(Wa2, wh + HO_WA2, 128, 128, tid, nt);
        cvt_tr(Wl1, wh + HO_WL1, 384, 384, tid, nt);
        cvt_tr(Wo1, wh + HO_WO1, 128, 128, tid, nt);
    }
}

// ---------------- K2: BN finalize + bias folds + prescaled W1T + W_LO fold ----------------
__global__ __launch_bounds__(256) void finalize_kernel(
        const float* __restrict__ gt, const float* __restrict__ btb,
        const float* __restrict__ gm, const float* __restrict__ bmb,
        const float* __restrict__ Wt1, const float* __restrict__ bt1,
        const float* __restrict__ Wm1, const float* __restrict__ bm1,
        const float* __restrict__ Wl2, const float* __restrict__ bl2,
        const float* __restrict__ Wo1, const float* __restrict__ bo1,
        float* __restrict__ ws, _Float16* __restrict__ wh) {
    __shared__ float red[256];
    __shared__ float statT[32], statM[16];
    __shared__ float shT[16], shM[8];
    __shared__ float saT[16], saM[8];
    __shared__ __attribute__((aligned(16))) _Float16 tlo[128 * 136];  // W_LO staging [k][o]
    const int t = threadIdx.x;
    {
        const int slot = t & 31, chunk = t >> 5;
        const float* p = ws + OFF_PART_T;
        float s = 0.f;
        for (int b = chunk * 32; b < chunk * 32 + 32; b++) s += p[b * 32 + slot];
        red[t] = s;
    }
    __syncthreads();
    if (t < 32) {
        float v = 0.f;
#pragma unroll
        for (int c = 0; c < 8; c++) v += red[t + 32 * c];
        statT[t] = v;
    }
    __syncthreads();
    {
        float s = 0.f;
        if (t < 128) {
            const int slot = t & 15, chunk = t >> 4;
            const float* p = ws + OFF_PART_M;
            for (int b = chunk * 8; b < chunk * 8 + 8; b++) s += p[b * 16 + slot];
        }
        red[t] = s;
    }
    __syncthreads();
    if (t < 16) {
        float v = 0.f;
#pragma unroll
        for (int c = 0; c < 8; c++) v += red[t + 16 * c];
        statM[t] = v;
    }
    __syncthreads();
    if (t < 16) {
        float mu  = statT[t] / (float)N_T;
        float var = statT[16 + t] / (float)N_T - mu * mu;
        float a   = gt[t] * rsqrtf(var + EPS);
        ws[OFF_AT + t] = a;
        float b = btb[t] - mu * a;
        ws[OFF_BT + t] = b;
        shT[t] = b;
        saT[t] = a;
    } else if (t < 24) {
        int c = t - 16;
        float mu  = statM[c] / (float)N_M;
        float var = statM[8 + c] / (float)N_M - mu * mu;
        float a   = gm[c] * rsqrtf(var + EPS);
        ws[OFF_AM + c] = a;
        float b = bmb[c] - mu * a;
        ws[OFF_BM + c] = b;
        shM[c] = b;
        saM[c] = a;
    }
    __syncthreads();
    if (t < 128) {
        float s = bt1[t];
#pragma unroll
        for (int k = 0; k < 16; k++) s += shT[k] * Wt1[k * 128 + t];
        ws[OFF_BT1F + t] = s;
        _Float16 row[32];
#pragma unroll
        for (int k = 0; k < 16; k++) row[k] = (_Float16)(Wt1[k * 128 + t] * saT[k]);
        float bh = (float)(_Float16)s;
        row[16] = (_Float16)s;
        row[17] = (_Float16)(s - bh);
#pragma unroll
        for (int k = 18; k < 32; k++) row[k] = (_Float16)0.f;
#pragma unroll
        for (int q = 0; q < 4; q++)
            *(f16x8*)(wh + HO_WT1 + t * 32 + q * 8) = *(const f16x8*)(row + q * 8);
    } else {
        int c = t - 128;
        float s = bm1[c];
#pragma unroll
        for (int k = 0; k < 8; k++) s += shM[k] * Wm1[k * 128 + c];
        ws[OFF_BM1F + c] = s;
        _Float16 row[32];
#pragma unroll
        for (int k = 0; k < 8; k++) row[k] = (_Float16)(Wm1[k * 128 + c] * saM[k]);
        float bh = (float)(_Float16)s;
        row[8] = (_Float16)s;
        row[9] = (_Float16)(s - bh);
#pragma unroll
        for (int k = 10; k < 32; k++) row[k] = (_Float16)0.f;
#pragma unroll
        for (int q = 0; q < 4; q++)
            *(f16x8*)(wh + HO_WM1 + c * 32 + q * 8) = *(const f16x8*)(row + q * 8);
    }
    // ---- W_LO = f16(Wl2) @ f16(Wo1): MFMA, LDS-staged, coalesced write to WT layout ----
    {
        const int lane = t & 63, wv = t >> 6;
        const int r = lane & 15, gq = lane >> 4;
        const int m0 = 2 * wv;
        f16x8 wo1f[2][4];
        ld128(wo1f, wh + HO_WO1, 128, 0, m0, r, gq);
#pragma unroll
        for (int half = 0; half < 2; half++) {
            f32x4 acc[4][2];
            zacc(acc);
#pragma unroll
            for (int rg = 0; rg < 4; rg++) {
                const int k = half * 64 + rg * 16 + r;
#pragma unroll
                for (int ks = 0; ks < 4; ks++) {
                    const float* src = Wl2 + k * 128 + ks * 32 + gq * 8;
                    float4 a = *(const float4*)(src);
                    float4 b = *(const float4*)(src + 4);
                    f16x8 bf;
                    bf[0] = (_Float16)a.x; bf[1] = (_Float16)a.y;
                    bf[2] = (_Float16)a.z; bf[3] = (_Float16)a.w;
                    bf[4] = (_Float16)b.x; bf[5] = (_Float16)b.y;
                    bf[6] = (_Float16)b.z; bf[7] = (_Float16)b.w;
                    acc[rg][0] = MFMA16(wo1f[0][ks], bf, acc[rg][0]);
                    acc[rg][1] = MFMA16(wo1f[1][ks], bf, acc[rg][1]);
                }
            }
#pragma unroll
            for (int rg = 0; rg < 4; rg++) {
                const int k = half * 64 + rg * 16 + r;
#pragma unroll
                for (int mi = 0; mi < 2; mi++) {
                    f16x4 hv;
#pragma unroll
                    for (int j = 0; j < 4; j++) hv[j] = (_Float16)acc[rg][mi][j];
                    *(f16x4*)(tlo + k * 136 + (m0 + mi) * 16 + gq * 4) = hv;
                }
            }
        }
    }
    __syncthreads();
    {
        // coalesced write-out: WloT[o*128 + k] = tlo[k][o]
        const int o = t >> 1, kh = (t & 1) * 64;
#pragma unroll
        for (int q = 0; q < 8; q++) {
            _Float16 buf[8];
#pragma unroll
            for (int e = 0; e < 8; e++) buf[e] = tlo[(kh + q * 8 + e) * 136 + o];
            *(f16x8*)(wh + HO_WLO + o * 128 + kh + q * 8) = *(const f16x8*)buf;
        }
    }
    if (t < 128) {
        float s = bo1[t];
        for (int k = 0; k < 128; k++) s += bl2[k] * Wo1[k * 128 + t];
        ws[OFF_BFOLD + t] = s;
    }
}

// ---------------- K3: seg_tile4 — 1250 blocks x 4 tiles, 17.4KB LDS, weights loaded once ----------------
__global__ __launch_bounds__(256, 3) void seg_tile4(
        const _Float16* __restrict__ xt16, const _Float16* __restrict__ xm16,
        const _Float16* __restrict__ wh, const float* __restrict__ wsf,
        const float* __restrict__ bt2, const float* __restrict__ bm2,
        float* __restrict__ meanT, float* __restrict__ meanM) {
    __shared__ __attribute__((aligned(16))) _Float16 h1s[64 * 136];
    const int t = threadIdx.x, lane = t & 63, w = t >> 6;
    const int r = lane & 15, gq = lane >> 4;
    const int m0 = 2 * w;
    const bool taskb = (blockIdx.x < B);
    const _Float16* W1T = wh + (taskb ? HO_WT1 : HO_WM1);
    const _Float16* W2T = wh + (taskb ? HO_WT2 : HO_WM2);
    const float* b1f = wsf + (taskb ? OFF_BT1F : OFF_BM1F);
    const float* b2  = taskb ? bt2 : bm2;
    const _Float16* x16 = taskb ? xt16 : xm16;
    const int ROWS = taskb ? T_PER : M_PER;
    const int CIN  = taskb ? 16 : 8;
    // --- weight prologue: once per block ---
    f16x8 w1[2]; ld32(w1, W1T, m0, r, gq);
    f16x8 w2[2][4]; ld128(w2, W2T, 128, 0, m0, r, gq);
    f32x4 b1v[2], b2v[2];
#pragma unroll
    for (int mi = 0; mi < 2; mi++) {
        b1v[mi] = *(const f32x4*)(b1f + (m0 + mi) * 16 + gq * 4);
        b2v[mi] = *(const f32x4*)(b2 + (m0 + mi) * 16 + gq * 4);
    }
    f16x8 z8;
#pragma unroll
    for (int e = 0; e < 8; e++) z8[e] = (_Float16)0.f;
    const bool loader = taskb ? (gq < 2) : (gq == 0);
    const int gb = taskb ? blockIdx.x : 0;
    const int mg0 = taskb ? 0 : (blockIdx.x - B) * 4;
    const f32x4 zf = (f32x4){0.f, 0.f, 0.f, 0.f};
    f32x4 rs[2];
    rs[0] = zf; rs[1] = zf;
    // tile 0 x
    f16x8 xb[4];
    {
        const int g0 = taskb ? gb : mg0;
#pragma unroll
        for (int rg = 0; rg < 4; rg++) {
            int row = rg * 16 + r;
            int cl = (row < ROWS) ? row : (ROWS - 1);
            xb[rg] = loader ? *(const f16x8*)(x16 + (g0 * ROWS + cl) * CIN + gq * 8) : z8;
        }
    }
    for (int it = 0; it < 4; it++) {
        const int g = taskb ? gb : (mg0 + it);
        const int rbase = taskb ? (it * 64) : 0;
        f32x4 acc[4][2];
        zacc(acc);
        mm32g(w1, xb, acc);
        epi_cs(acc, b1v, h1s, 136, m0, r, gq, true);
        __syncthreads();
        // prefetch next tile's x: drains at end-of-tile barrier, hidden under GEMM2+accum
        if (it < 3) {
            const int gn = taskb ? gb : (mg0 + it + 1);
            const int rbn = taskb ? ((it + 1) * 64) : 0;
#pragma unroll
            for (int rg = 0; rg < 4; rg++) {
                int row = rbn + rg * 16 + r;
                int cl = (row < ROWS) ? row : (ROWS - 1);
                xb[rg] = loader ? *(const f16x8*)(x16 + (gn * ROWS + cl) * CIN + gq * 8) : z8;
            }
        }
        zacc(acc);
        mm128(w2, h1s, 136, r, gq, acc);
        if (taskb) {
            if (rbase + 64 <= ROWS) {
#pragma unroll
                for (int rg = 0; rg < 4; rg++)
#pragma unroll
                    for (int mi = 0; mi < 2; mi++)
#pragma unroll
                        for (int j = 0; j < 4; j++)
                            rs[mi][j] += fmaxf(acc[rg][mi][j] + b2v[mi][j], 0.f);
            } else {
#pragma unroll
                for (int rg = 0; rg < 4; rg++) {
                    const float mk = ((rbase + rg * 16 + r) < ROWS) ? 1.f : 0.f;
#pragma unroll
                    for (int mi = 0; mi < 2; mi++)
#pragma unroll
                        for (int j = 0; j < 4; j++)
                            rs[mi][j] = fmaf(fmaxf(acc[rg][mi][j] + b2v[mi][j], 0.f), mk, rs[mi][j]);
                }
            }
        } else {
            // machine: per-tile (per-graph) reduce + store
            f32x4 ms[2];
            ms[0] = zf; ms[1] = zf;
#pragma unroll
            for (int rg = 0; rg < 4; rg++) {
                const float mk = ((rg * 16 + r) < ROWS) ? 1.f : 0.f;
#pragma unroll
                for (int mi = 0; mi < 2; mi++)
#pragma unroll
                    for (int j = 0; j < 4; j++)
                        ms[mi][j] = fmaf(fmaxf(acc[rg][mi][j] + b2v[mi][j], 0.f), mk, ms[mi][j]);
            }
#pragma unroll
            for (int mi = 0; mi < 2; mi++)
#pragma unroll
                for (int j = 0; j < 4; j++) {
                    float v = ms[mi][j];
                    v += __shfl_xor(v, 1); v += __shfl_xor(v, 2);
                    v += __shfl_xor(v, 4); v += __shfl_xor(v, 8);
                    ms[mi][j] = v;
                }
            if (r == 0) {
                const float inv = 1.f / (float)M_PER;
#pragma unroll
                for (int mi = 0; mi < 2; mi++) {
                    f32x4 st = ms[mi] * inv;
                    *(f32x4*)(meanM + g * H + (m0 + mi) * 16 + gq * 4) = st;
                }
            }
        }
        if (it < 3) __syncthreads();  // protect h1s before next tile's epi write
    }
    if (taskb) {
#pragma unroll
        for (int mi = 0; mi < 2; mi++)
#pragma unroll
            for (int j = 0; j < 4; j++) {
                float v = rs[mi][j];
                v += __shfl_xor(v, 1); v += __shfl_xor(v, 2);
                v += __shfl_xor(v, 4); v += __shfl_xor(v, 8);
                rs[mi][j] = v;
            }
        if (r == 0) {
            const float inv = 1.f / (float)T_PER;
#pragma unroll
            for (int mi = 0; mi < 2; mi++) {
                f32x4 st = rs[mi] * inv;
                *(f32x4*)(meanT + gb * H + (m0 + mi) * 16 + gq * 4) = st;
            }
        }
    }
}

// ---------------- K4: graph aggr MLP + fused aggr@Wl1b (16 graphs/block) ----------------
__global__ __launch_bounds__(256) void aggr_kernel(const float* __restrict__ meanT, const float* __restrict__ meanM,
        const _Float16* __restrict__ Wa1T, const float* __restrict__ ba1,
        const _Float16* __restrict__ Wa2T, const float* __restrict__ ba2,
        const _Float16* __restrict__ Wl1T, const float* __restrict__ bl1,
        float* __restrict__ agg2) {
    __shared__ __attribute__((aligned(16))) _Float16 cin[16 * 264];
    __shared__ __attribute__((aligned(16))) _Float16 h1s[16 * 136];
    __shared__ __attribute__((aligned(16))) _Float16 ags[16 * 136];
    const int t = threadIdx.x, lane = t & 63, wave = t >> 6;
    const int r = lane & 15, gq = lane >> 4;
    const int m0 = 2 * wave;
    const int g0 = blockIdx.x * 16;
    f16x8 wa1[2][8], wa2[2][4], wl1b[2][4];
#pragma unroll
    for (int mi = 0; mi < 2; mi++)
#pragma unroll
        for (int ks = 0; ks < 8; ks++)
            wa1[mi][ks] = *(const f16x8*)(Wa1T + ((m0 + mi) * 16 + r) * 256 + ks * 32 + gq * 8);
    ld128(wa2, Wa2T, 128, 0, m0, r, gq);
    ld128(wl1b, Wl1T, 384, 128, m0, r, gq);
    f32x4 b1v[2], b2v[2], blv[2];
#pragma unroll
    for (int mi = 0; mi < 2; mi++) {
        b1v[mi] = *(const f32x4*)(ba1 + (m0 + mi) * 16 + gq * 4);
        b2v[mi] = *(const f32x4*)(ba2 + (m0 + mi) * 16 + gq * 4);
        blv[mi] = *(const f32x4*)(bl1 + (m0 + mi) * 16 + gq * 4);
    }
    for (int e = t; e < 16 * 64; e += 256) {
        int j = e >> 6, c4 = e & 63;
        int g = g0 + j;
        float4 v = {0.f, 0.f, 0.f, 0.f};
        if (g < B) v = (c4 < 32) ? *(const float4*)(meanT + g * H + c4 * 4)
                                 : *(const float4*)(meanM + g * H + (c4 - 32) * 4);
        f16x4 hv;
        hv[0] = (_Float16)v.x; hv[1] = (_Float16)v.y; hv[2] = (_Float16)v.z; hv[3] = (_Float16)v.w;
        *(f16x4*)(cin + j * 264 + c4 * 4) = hv;
    }
    __syncthreads();
    f32x4 a0 = {0.f, 0.f, 0.f, 0.f}, a1 = {0.f, 0.f, 0.f, 0.f};
    {
        const _Float16* bp = cin + r * 264 + gq * 8;
#pragma unroll
        for (int ks = 0; ks < 8; ks++) {
            const f16x8 bf = *(const f16x8*)(bp + ks * 32);
            a0 = MFMA16(wa1[0][ks], bf, a0);
            a1 = MFMA16(wa1[1][ks], bf, a1);
        }
    }
    {
        f16x4 h0, h1v;
#pragma unroll
        for (int j = 0; j < 4; j++) {
            h0[j]  = (_Float16)fmaxf(a0[j] + b1v[0][j], 0.f);
            h1v[j] = (_Float16)fmaxf(a1[j] + b1v[1][j], 0.f);
        }
        *(f16x4*)(h1s + r * 136 + m0 * 16 + gq * 4) = h0;
        *(f16x4*)(h1s + r * 136 + (m0 + 1) * 16 + gq * 4) = h1v;
    }
    __syncthreads();
    a0 = (f32x4){0.f, 0.f, 0.f, 0.f}; a1 = (f32x4){0.f, 0.f, 0.f, 0.f};
    {
        const _Float16* bp = h1s + r * 136 + gq * 8;
#pragma unroll
        for (int ks = 0; ks < 4; ks++) {
            const f16x8 bf = *(const f16x8*)(bp + ks * 32);
            a0 = MFMA16(wa2[0][ks], bf, a0);
            a1 = MFMA16(wa2[1][ks], bf, a1);
        }
    }
    {
        f16x4 h0, h1v;
#pragma unroll
        for (int j = 0; j < 4; j++) {
            h0[j]  = (_Float16)(a0[j] + b2v[0][j]);
            h1v[j] = (_Float16)(a1[j] + b2v[1][j]);
        }
        *(f16x4*)(ags + r * 136 + m0 * 16 + gq * 4) = h0;
        *(f16x4*)(ags + r * 136 + (m0 + 1) * 16 + gq * 4) = h1v;
    }
    __syncthreads();
    a0 = (f32x4){0.f, 0.f, 0.f, 0.f}; a1 = (f32x4){0.f, 0.f, 0.f, 0.f};
    {
        const _Float16* bp = ags + r * 136 + gq * 8;
#pragma unroll
        for (int ks = 0; ks < 4; ks++) {
            const f16x8 bf = *(const f16x8*)(bp + ks * 32);
            a0 = MFMA16(wl1b[0][ks], bf, a0);
            a1 = MFMA16(wl1b[1][ks], bf, a1);
        }
    }
    if (g0 + r < B) {
        *(f32x4*)(agg2 + (g0 + r) * H + m0 * 16 + gq * 4) = a0 + blv[0];
        *(f32x4*)(agg2 + (g0 + r) * H + (m0 + 1) * 16 + gq * 4) = a1 + blv[1];
    }
}

// ---------------- K5: label-row head (r6 structure, L2+L3 folded into one W_LO stage) ----------------
__global__ __launch_bounds__(256) void label_kernel(
        const float* __restrict__ xt,
        const _Float16* __restrict__ xt16, const _Float16* __restrict__ xm16,
        const _Float16* __restrict__ Wt1T, const float* __restrict__ bt1f,
        const _Float16* __restrict__ Wt2T, const float* __restrict__ bt2,
        const _Float16* __restrict__ Wm1T, const float* __restrict__ bm1f,
        const _Float16* __restrict__ Wm2T, const float* __restrict__ bm2,
        const _Float16* __restrict__ Wl1T,
        const _Float16* __restrict__ WloT, const float* __restrict__ bfold,
        const float* __restrict__ Wo2, const float* __restrict__ bo2,
        const float* __restrict__ agg2,
        const int* __restrict__ tbatch, const int* __restrict__ lidx,
        float* __restrict__ out) {
    __shared__ __attribute__((aligned(16))) _Float16 xs_t[64 * 40];
    __shared__ __attribute__((aligned(16))) _Float16 xs_m[64 * 40];
    __shared__ __attribute__((aligned(16))) _Float16 h1s[64 * 136];
    __shared__ __attribute__((aligned(16))) _Float16 cat[64 * 264];  // [th | mh]
    __shared__ float psum[4][64];
    __shared__ int ridx[64], gidx[64], midx[64];
    const int t = threadIdx.x;
    const int lane = t & 63, wave = t >> 6;
    const int r = lane & 15, gq = lane >> 4;
    const int m0 = 2 * wave;
    if (t < 64) {
        int i = blockIdx.x * 64 + t;
        int rr = (i < N_LBL) ? lidx[i] : 0;
        ridx[t] = rr;
        int gg = tbatch[rr];
        gidx[t] = gg;
        float tv = xt[rr * 16 + 1];
        midx[t] = (tv == -1.0f) ? -1 : ((int)tv + gg * M_PER);
    }
    __syncthreads();
    f16x4 z4; z4[0] = z4[1] = z4[2] = z4[3] = (_Float16)0.f;
    {
        int j = t >> 2, part = t & 3;
        f16x4 hv = *(const f16x4*)(xt16 + ridx[j] * 16 + part * 4);
        *(f16x4*)(xs_t + j * 40 + part * 4) = hv;
        *(f16x4*)(xs_t + j * 40 + 16 + part * 4) = z4;
    }
    if (t < 128) {
        int j = t >> 1, part = t & 1;
        int m = midx[j];
        f16x4 hv = z4;
        if (m >= 0) hv = *(const f16x4*)(xm16 + m * 8 + part * 4);
        *(f16x4*)(xs_m + j * 40 + part * 4) = hv;
#pragma unroll
        for (int q = 0; q < 3; q++)
            *(f16x4*)(xs_m + j * 40 + 8 + part * 12 + q * 4) = z4;
    }
    __syncthreads();
    f32x4 agg2v[4][2];
#pragma unroll
    for (int rg = 0; rg < 4; rg++)
#pragma unroll
        for (int mi = 0; mi < 2; mi++)
            agg2v[rg][mi] = *(const f32x4*)(agg2 + gidx[rg * 16 + r] * H + (m0 + mi) * 16 + gq * 4);
    f32x4 acc[4][2];
    // --- th ---
    f16x8 wt1[2]; ld32(wt1, Wt1T, m0, r, gq);
    f16x8 wt2[2][4]; ld128(wt2, Wt2T, 128, 0, m0, r, gq);
    f32x4 bva[2], bvb[2];
#pragma unroll
    for (int mi = 0; mi < 2; mi++) {
        bva[mi] = *(const f32x4*)(bt1f + (m0 + mi) * 16 + gq * 4);
        bvb[mi] = *(const f32x4*)(bt2 + (m0 + mi) * 16 + gq * 4);
    }
    zacc(acc);
    mm32(wt1, xs_t, 40, r, gq, acc);
    epi_cs(acc, bva, h1s, 136, m0, r, gq, true);
    f16x8 wm1[2]; ld32(wm1, Wm1T, m0, r, gq);
    __syncthreads();
    zacc(acc);
    mm128(wt2, h1s, 136, r, gq, acc);
    epi_cs(acc, bvb, cat, 264, m0, r, gq, true);
    f16x8 wm2[2][4]; ld128(wm2, Wm2T, 128, 0, m0, r, gq);
    __syncthreads();
    // --- mh ---
#pragma unroll
    for (int mi = 0; mi < 2; mi++) {
        bva[mi] = *(const f32x4*)(bm1f + (m0 + mi) * 16 + gq * 4);
        bvb[mi] = *(const f32x4*)(bm2 + (m0 + mi) * 16 + gq * 4);
    }
    zacc(acc);
    mm32(wm1, xs_m, 40, r, gq, acc);
    epi_cs(acc, bva, h1s, 136, m0, r, gq, true);
    f16x8 wl1a[2][4]; ld128(wl1a, Wl1T, 384, 0, m0, r, gq);
    __syncthreads();
    zacc(acc);
    mm128(wm2, h1s, 136, r, gq, acc);
#pragma unroll
    for (int rg = 0; rg < 4; rg++) {
        const bool sent = (midx[rg * 16 + r] < 0);
#pragma unroll
        for (int mi = 0; mi < 2; mi++) {
            f16x4 hv;
#pragma unroll
            for (int j = 0; j < 4; j++) {
                float v = fmaxf(acc[rg][mi][j] + bvb[mi][j], 0.f);
                hv[j] = (_Float16)(sent ? 0.f : v);
            }
            *(f16x4*)(cat + (rg * 16 + r) * 264 + 128 + (m0 + mi) * 16 + gq * 4) = hv;
        }
    }
    f16x8 wl1c[2][4]; ld128(wl1c, Wl1T, 384, 256, m0, r, gq);
    __syncthreads();
    // --- head L1 (+agg2 epi) ---
    zacc(acc);
    mm128(wl1a, cat, 264, r, gq, acc);
    mm128(wl1c, cat + 128, 264, r, gq, acc);
#pragma unroll
    for (int rg = 0; rg < 4; rg++)
#pragma unroll
        for (int mi = 0; mi < 2; mi++) {
            f16x4 hv;
#pragma unroll
            for (int j = 0; j < 4; j++)
                hv[j] = (_Float16)fmaxf(acc[rg][mi][j] + agg2v[rg][mi][j], 0.f);
            *(f16x4*)(h1s + (rg * 16 + r) * 136 + (m0 + mi) * 16 + gq * 4) = hv;
        }
    f16x8 wlo[2][4]; ld128(wlo, WloT, 128, 0, m0, r, gq);
    __syncthreads();
    // --- head LO (folded L2@Wo1, fp32 bias) + dot Wo2 ---
#pragma unroll
    for (int mi = 0; mi < 2; mi++) bva[mi] = *(const f32x4*)(bfold + (m0 + mi) * 16 + gq * 4);
    f32x4 wo2v[2];
#pragma unroll
    for (int mi = 0; mi < 2; mi++) wo2v[mi] = *(const f32x4*)(Wo2 + (m0 + mi) * 16 + gq * 4);
    zacc(acc);
    mm128(wlo, h1s, 136, r, gq, acc);
#pragma unroll
    for (int rg = 0; rg < 4; rg++) {
        float pv = 0.f;
#pragma unroll
        for (int mi = 0; mi < 2; mi++)
#pragma unroll
            for (int j = 0; j < 4; j++)
                pv += fmaxf(acc[rg][mi][j] + bva[mi][j], 0.f) * wo2v[mi][j];
        pv += __shfl_xor(pv, 16);
        pv += __shfl_xor(pv, 32);
        if (lane < 16) psum[wave][rg * 16 + lane] = pv;
    }
    __syncthreads();
    if (t < 64) {
        int i = blockIdx.x * 64 + t;
        if (i < N_LBL)
            out[i] = psum[0][t] + psum[1][t] + psum[2][t] + psum[3][t] + bo2[0];
    }
}

extern "C" void kernel_launch(void* const* d_in, const int* in_sizes, int n_in,
                              void* d_out, int out_size, void* d_ws, size_t ws_size,
                              hipStream_t stream) {
    const float* xt  = (const float*)d_in[0];
    const float* xm  = (const float*)d_in[1];
    const float* gt  = (const float*)d_in[2];
    const float* btb = (const float*)d_in[3];
    const float* Wt1 = (const float*)d_in[4];  const float* bt1 = (const float*)d_in[5];
    const float* Wt2 = (const float*)d_in[6];  const float* bt2 = (const float*)d_in[7];
    const float* gm  = (const float*)d_in[8];  const float* bmb = (const float*)d_in[9];
    const float* Wm1 = (const float*)d_in[10]; const float* bm1 = (const float*)d_in[11];
    const float* Wm2 = (const float*)d_in[12]; const float* bm2 = (const float*)d_in[13];
    const float* Wa1 = (const float*)d_in[14]; const float* ba1 = (const float*)d_in[15];
    const float* Wa2 = (const float*)d_in[16]; const float* ba2 = (const float*)d_in[17];
    const float* Wl1 = (const float*)d_in[18]; const float* bl1 = (const float*)d_in[19];
    const float* Wl2 = (const float*)d_in[20]; const float* bl2 = (const float*)d_in[21];
    const float* Wo1 = (const float*)d_in[22]; const float* bo1 = (const float*)d_in[23];
    const float* Wo2 = (const float*)d_in[24]; const float* bo2 = (const float*)d_in[25];
    const int* tb  = (const int*)d_in[26];
    const int* lix = (const int*)d_in[28];
    float* wsf = (float*)d_ws;
    _Float16* wh = (_Float16*)(wsf + OFF_HALF);
    _Float16* xt16 = wh + HO_XT16;
    _Float16* xm16 = wh + HO_XM16;
    float* outp = (float*)d_out;

    stats_prep_kernel<<<NB_T + NB_M + NB_P, 256, 0, stream>>>(
        xt, xm, xt16, xm16, Wt2, Wm2, Wa1, Wa2, Wl1, Wo1, wsf, wh);
    finalize_kernel<<<1, 256, 0, stream>>>(gt, btb, gm, bmb, Wt1, bt1, Wm1, bm1,
                                           Wl2, bl2, Wo1, bo1, wsf, wh);
    seg_tile4<<<B + 250, 256, 0, stream>>>(xt16, xm16, wh, wsf, bt2, bm2,
                                           wsf + OFF_MEANT, wsf + OFF_MEANM);
    aggr_kernel<<<(B + 15) / 16, 256, 0, stream>>>(wsf + OFF_MEANT, wsf + OFF_MEANM,
                                                   wh + HO_WA1, ba1, wh + HO_WA2, ba2,
                                                   wh + HO_WL1, bl1, wsf + OFF_AGG2);
    label_kernel<<<(N_LBL + 63) / 64, 256, 0, stream>>>(xt, xt16, xm16,
                                                        wh + HO_WT1, wsf + OFF_BT1F, wh + HO_WT2, bt2,
                                                        wh + HO_WM1, wsf + OFF_BM1F, wh + HO_WM2, bm2,
                                                        wh + HO_WL1,
                                                        wh + HO_WLO, wsf + OFF_BFOLD,
                                                        Wo2, bo2,
                                                        wsf + OFF_AGG2, tb, lix, outp);
}

// Round 9
// 71.202 us; speedup vs baseline: 1.2259x; 1.2259x over previous
//
#include <hip/hip_runtime.h>

// Problem constants (fixed by setup_inputs)
constexpr int B     = 1000;
constexpr int T_PER = 250;
constexpr int M_PER = 50;
constexpr int N_T   = B * T_PER;   // 250000
constexpr int N_M   = B * M_PER;   // 50000
constexpr int H     = 128;
constexpr int N_LBL = 25000;
constexpr float EPS = 1e-05f;

constexpr int NB_T = 256;  // bn_stats blocks (tasks)
constexpr int NB_M = 64;   // bn_stats blocks (machines)
constexpr int NB_P = 64;   // prep blocks
constexpr int NB_F = 65;   // fold blocks: 64 x W_LO + 1 x bfold (static, parallel)

// ---- ws layout ----
constexpr int OFF_PART_T = 0;                       // 256 blocks * 32
constexpr int OFF_PART_M = OFF_PART_T + NB_T * 32;  // 64 blocks * 16
constexpr int OFF_AT     = OFF_PART_M + NB_M * 16;  // 16
constexpr int OFF_BT     = OFF_AT + 16;
constexpr int OFF_AM     = OFF_BT + 16;
constexpr int OFF_BM     = OFF_AM + 8;
constexpr int OFF_BT1F   = OFF_BM + 8;              // 128 folded bt1
constexpr int OFF_BM1F   = OFF_BT1F + 128;          // 128 folded bm1
constexpr int OFF_MEANT  = OFF_BM1F + 128;          // B*H task means
constexpr int OFF_MEANM  = OFF_MEANT + B * H;       // B*H machine means
constexpr int OFF_AGG2   = OFF_MEANM + B * H;       // B*H aggr output (Wl1b-folded)
constexpr int OFF_BFOLD  = OFF_AGG2 + B * H;        // 128: bl2@Wo1 + bo1
constexpr int OFF_HALF   = OFF_BFOLD + 128;         // fp16 region (16B aligned)
// fp16 region (half offsets from wh)
constexpr int HO_WT1  = 0;       // 128*32 (prescaled + bias cols 16,17 — written by finalize)
constexpr int HO_WT2  = 4096;    // 128*128
constexpr int HO_WM1  = 20480;   // 128*32 (prescaled + bias cols 8,9)
constexpr int HO_WM2  = 24576;   // 128*128
constexpr int HO_WA1  = 40960;   // 128*256
constexpr int HO_WA2  = 73728;   // 128*128
constexpr int HO_WL1  = 90112;   // 128*384
constexpr int HO_WLO  = 139264;  // 128*128: (Wl2@Wo1) in WT layout — written by stats_prep fold
constexpr int HO_WO1  = 155648;  // 128*128 (slot unused now; offsets kept)
constexpr int HO_XT16 = 172032;             // N_T*16 f16
constexpr int HO_XM16 = HO_XT16 + N_T * 16; // N_M*8 f16

typedef _Float16 f16x8 __attribute__((ext_vector_type(8)));
typedef _Float16 f16x4 __attribute__((ext_vector_type(4)));
typedef float f32x4 __attribute__((ext_vector_type(4)));

#define MFMA16(a, b, c) __builtin_amdgcn_mfma_f32_16x16x32_f16(a, b, c, 0, 0, 0)

// ---------------- column-split MFMA helpers ----------------
__device__ __forceinline__ void zacc(f32x4 acc[4][2]) {
#pragma unroll
    for (int rg = 0; rg < 4; rg++)
#pragma unroll
        for (int mi = 0; mi < 2; mi++) acc[rg][mi] = (f32x4){0.f, 0.f, 0.f, 0.f};
}

__device__ __forceinline__ void ld32(f16x8 w[2], const _Float16* __restrict__ WT,
                                     int m0, int r, int gq) {
#pragma unroll
    for (int mi = 0; mi < 2; mi++)
        w[mi] = *(const f16x8*)(WT + ((m0 + mi) * 16 + r) * 32 + gq * 8);
}

__device__ __forceinline__ void ld128(f16x8 w[2][4], const _Float16* __restrict__ WT,
                                      int lda, int k0, int m0, int r, int gq) {
#pragma unroll
    for (int mi = 0; mi < 2; mi++)
#pragma unroll
        for (int ks = 0; ks < 4; ks++)
            w[mi][ks] = *(const f16x8*)(WT + ((m0 + mi) * 16 + r) * lda + k0 + ks * 32 + gq * 8);
}

// GEMM1 with B-fragments in registers
__device__ __forceinline__ void mm32g(const f16x8 w[2], const f16x8 xb[4], f32x4 acc[4][2]) {
#pragma unroll
    for (int rg = 0; rg < 4; rg++) {
        acc[rg][0] = MFMA16(w[0], xb[rg], acc[rg][0]);
        acc[rg][1] = MFMA16(w[1], xb[rg], acc[rg][1]);
    }
}

__device__ __forceinline__ void mm32(const f16x8 w[2], const _Float16* __restrict__ act,
                                     int rstride, int r, int gq, f32x4 acc[4][2]) {
#pragma unroll
    for (int rg = 0; rg < 4; rg++) {
        const f16x8 bf = *(const f16x8*)(act + (rg * 16 + r) * rstride + gq * 8);
        acc[rg][0] = MFMA16(w[0], bf, acc[rg][0]);
        acc[rg][1] = MFMA16(w[1], bf, acc[rg][1]);
    }
}

__device__ __forceinline__ void mm128(const f16x8 w[2][4], const _Float16* __restrict__ act,
                                      int rstride, int r, int gq, f32x4 acc[4][2]) {
#pragma unroll
    for (int rg = 0; rg < 4; rg++)
#pragma unroll
        for (int ks = 0; ks < 4; ks++) {
            const f16x8 bf = *(const f16x8*)(act + (rg * 16 + r) * rstride + ks * 32 + gq * 8);
            acc[rg][0] = MFMA16(w[0][ks], bf, acc[rg][0]);
            acc[rg][1] = MFMA16(w[1][ks], bf, acc[rg][1]);
        }
}

__device__ __forceinline__ void epi_cs(const f32x4 acc[4][2], const f32x4 bv[2],
                                       _Float16* __restrict__ dst, int dstride,
                                       int m0, int r, int gq, bool relu) {
#pragma unroll
    for (int rg = 0; rg < 4; rg++)
#pragma unroll
        for (int mi = 0; mi < 2; mi++) {
            f16x4 hv;
#pragma unroll
            for (int j = 0; j < 4; j++) {
                float v = acc[rg][mi][j] + bv[mi][j];
                if (relu) v = fmaxf(v, 0.f);
                hv[j] = (_Float16)v;
            }
            *(f16x4*)(dst + (rg * 16 + r) * dstride + (m0 + mi) * 16 + gq * 4) = hv;
        }
}

// ---------------- K1: BN partial stats + x->f16 dump + weight cvt + static W_LO/bfold fold ----------------
template <int C, int NB>
__device__ __forceinline__ void stats_body(const float* __restrict__ x,
                                           _Float16* __restrict__ x16, int nelem,
                                           float* __restrict__ part, int blk, int t,
                                           float* ls, float* lq) {
    float s = 0.f, q = 0.f;
    for (int e = blk * 256 + t; e < nelem; e += NB * 256) {
        float v = x[e];
        s += v;
        q += v * v;
        x16[e] = (_Float16)v;
    }
    ls[t] = s; lq[t] = q;
    __syncthreads();
    if (t < C) {
        float S = 0.f, Q = 0.f;
        for (int u = t; u < 256; u += C) { S += ls[u]; Q += lq[u]; }
        part[blk * 2 * C + t] = S;
        part[blk * 2 * C + C + t] = Q;
    }
}

__device__ __forceinline__ void cvt_tr(const float* __restrict__ src, _Float16* __restrict__ dst,
                                       int K, int Kp, int tid, int nt) {
    for (int idx = tid; idx < 128 * Kp; idx += nt) {
        int c = idx / Kp, k = idx - c * Kp;
        float v = (k < K) ? src[k * 128 + c] : 0.f;
        dst[idx] = (_Float16)v;
    }
}

__global__ __launch_bounds__(256) void stats_prep_kernel(
        const float* __restrict__ xt, const float* __restrict__ xm,
        _Float16* __restrict__ xt16, _Float16* __restrict__ xm16,
        const float* __restrict__ Wt2, const float* __restrict__ Wm2,
        const float* __restrict__ Wa1, const float* __restrict__ Wa2,
        const float* __restrict__ Wl1,
        const float* __restrict__ Wl2, const float* __restrict__ bl2,
        const float* __restrict__ Wo1, const float* __restrict__ bo1,
        float* __restrict__ wsf, _Float16* __restrict__ wh) {
    __shared__ float ls[256], lq[256];
    const int bid = blockIdx.x, t = threadIdx.x;
    if (bid < NB_T) {
        stats_body<16, NB_T>(xt, xt16, N_T * 16, wsf + OFF_PART_T, bid, t, ls, lq);
    } else if (bid < NB_T + NB_M) {
        stats_body<8, NB_M>(xm, xm16, N_M * 8, wsf + OFF_PART_M, bid - NB_T, t, ls, lq);
    } else if (bid < NB_T + NB_M + NB_P) {
        const int tid = (bid - NB_T - NB_M) * 256 + t;
        const int nt = NB_P * 256;
        cvt_tr(Wt2, wh + HO_WT2, 128, 128, tid, nt);
        cvt_tr(Wm2, wh + HO_WM2, 128, 128, tid, nt);
        cvt_tr(Wa1, wh + HO_WA1, 256, 256, tid, nt);
        cvt_tr(Wa2, wh + HO_WA2, 128, 128, tid, nt);
        cvt_tr(Wl1, wh + HO_WL1, 384, 384, tid, nt);
    } else if (bid < NB_T + NB_M + NB_P + 64) {
        // W_LO[k][o] = sum_c f16(Wl2[k][c]) * f16(Wo1[c][o]); stored WT: WloT[o*128+k].
        // One output per thread; Wo1 reads coalesced (o = t&127), Wl2 reads wave-broadcast.
        const int idx = (bid - NB_T - NB_M - NB_P) * 256 + t;  // [0, 16384)
        const int k = idx >> 7, o = idx & 127;
        float s = 0.f;
#pragma unroll 8
        for (int c = 0; c < 128; c++)
            s += (float)(_Float16)Wl2[k * 128 + c] * (float)(_Float16)Wo1[c * 128 + o];
        wh[HO_WLO + o * 128 + k] = (_Float16)s;
    } else {
        // bfold[o] = bo1[o] + sum_c bl2[c]*Wo1[c][o]  (fp32)
        if (t < 128) {
            float s = bo1[t];
#pragma unroll 8
            for (int c = 0; c < 128; c++) s += bl2[c] * Wo1[c * 128 + t];
            wsf[OFF_BFOLD + t] = s;
        }
    }
}

// ---------------- K2: BN finalize + bias folds + prescaled W1T/WM1T (single block, r6 form) ----------------
__global__ __launch_bounds__(256) void finalize_kernel(
        const float* __restrict__ gt, const float* __restrict__ btb,
        const float* __restrict__ gm, const float* __restrict__ bmb,
        const float* __restrict__ Wt1, const float* __restrict__ bt1,
        const float* __restrict__ Wm1, const float* __restrict__ bm1,
        float* __restrict__ ws, _Float16* __restrict__ wh) {
    __shared__ float red[256];
    __shared__ float statT[32], statM[16];
    __shared__ float shT[16], shM[8];
    __shared__ float saT[16], saM[8];
    const int t = threadIdx.x;
    {
        const int slot = t & 31, chunk = t >> 5;
        const float* p = ws + OFF_PART_T;
        float s = 0.f;
        for (int b = chunk * 32; b < chunk * 32 + 32; b++) s += p[b * 32 + slot];
        red[t] = s;
    }
    __syncthreads();
    if (t < 32) {
        float v = 0.f;
#pragma unroll
        for (int c = 0; c < 8; c++) v += red[t + 32 * c];
        statT[t] = v;
    }
    __syncthreads();
    {
        float s = 0.f;
        if (t < 128) {
            const int slot = t & 15, chunk = t >> 4;
            const float* p = ws + OFF_PART_M;
            for (int b = chunk * 8; b < chunk * 8 + 8; b++) s += p[b * 16 + slot];
        }
        red[t] = s;
    }
    __syncthreads();
    if (t < 16) {
        float v = 0.f;
#pragma unroll
        for (int c = 0; c < 8; c++) v += red[t + 16 * c];
        statM[t] = v;
    }
    __syncthreads();
    if (t < 16) {
        float mu  = statT[t] / (float)N_T;
        float var = statT[16 + t] / (float)N_T - mu * mu;
        float a   = gt[t] * rsqrtf(var + EPS);
        ws[OFF_AT + t] = a;
        float b = btb[t] - mu * a;
        ws[OFF_BT + t] = b;
        shT[t] = b;
        saT[t] = a;
    } else if (t < 24) {
        int c = t - 16;
        float mu  = statM[c] / (float)N_M;
        float var = statM[8 + c] / (float)N_M - mu * mu;
        float a   = gm[c] * rsqrtf(var + EPS);
        ws[OFF_AM + c] = a;
        float b = bmb[c] - mu * a;
        ws[OFF_BM + c] = b;
        shM[c] = b;
        saM[c] = a;
    }
    __syncthreads();
    if (t < 128) {
        float s = bt1[t];
#pragma unroll
        for (int k = 0; k < 16; k++) s += shT[k] * Wt1[k * 128 + t];
        ws[OFF_BT1F + t] = s;
        _Float16 row[32];
#pragma unroll
        for (int k = 0; k < 16; k++) row[k] = (_Float16)(Wt1[k * 128 + t] * saT[k]);
        float bh = (float)(_Float16)s;
        row[16] = (_Float16)s;
        row[17] = (_Float16)(s - bh);
#pragma unroll
        for (int k = 18; k < 32; k++) row[k] = (_Float16)0.f;
#pragma unroll
        for (int q = 0; q < 4; q++)
            *(f16x8*)(wh + HO_WT1 + t * 32 + q * 8) = *(const f16x8*)(row + q * 8);
    } else {
        int c = t - 128;
        float s = bm1[c];
#pragma unroll
        for (int k = 0; k < 8; k++) s += shM[k] * Wm1[k * 128 + c];
        ws[OFF_BM1F + c] = s;
        _Float16 row[32];
#pragma unroll
        for (int k = 0; k < 8; k++) row[k] = (_Float16)(Wm1[k * 128 + c] * saM[k]);
        float bh = (float)(_Float16)s;
        row[8] = (_Float16)s;
        row[9] = (_Float16)(s - bh);
#pragma unroll
        for (int k = 10; k < 32; k++) row[k] = (_Float16)0.f;
#pragma unroll
        for (int q = 0; q < 4; q++)
            *(f16x8*)(wh + HO_WM1 + c * 32 + q * 8) = *(const f16x8*)(row + q * 8);
    }
}

// ---------------- K3: seg_tile4 — 1250 blocks x 4 tiles, 17.4KB LDS, weights loaded once ----------------
__global__ __launch_bounds__(256, 3) void seg_tile4(
        const _Float16* __restrict__ xt16, const _Float16* __restrict__ xm16,
        const _Float16* __restrict__ wh, const float* __restrict__ wsf,
        const float* __restrict__ bt2, const float* __restrict__ bm2,
        float* __restrict__ meanT, float* __restrict__ meanM) {
    __shared__ __attribute__((aligned(16))) _Float16 h1s[64 * 136];
    const int t = threadIdx.x, lane = t & 63, w = t >> 6;
    const int r = lane & 15, gq = lane >> 4;
    const int m0 = 2 * w;
    const bool taskb = (blockIdx.x < B);
    const _Float16* W1T = wh + (taskb ? HO_WT1 : HO_WM1);
    const _Float16* W2T = wh + (taskb ? HO_WT2 : HO_WM2);
    const float* b1f = wsf + (taskb ? OFF_BT1F : OFF_BM1F);
    const float* b2  = taskb ? bt2 : bm2;
    const _Float16* x16 = taskb ? xt16 : xm16;
    const int ROWS = taskb ? T_PER : M_PER;
    const int CIN  = taskb ? 16 : 8;
    // --- weight prologue: once per block ---
    f16x8 w1[2]; ld32(w1, W1T, m0, r, gq);
    f16x8 w2[2][4]; ld128(w2, W2T, 128, 0, m0, r, gq);
    f32x4 b1v[2], b2v[2];
#pragma unroll
    for (int mi = 0; mi < 2; mi++) {
        b1v[mi] = *(const f32x4*)(b1f + (m0 + mi) * 16 + gq * 4);
        b2v[mi] = *(const f32x4*)(b2 + (m0 + mi) * 16 + gq * 4);
    }
    f16x8 z8;
#pragma unroll
    for (int e = 0; e < 8; e++) z8[e] = (_Float16)0.f;
    const bool loader = taskb ? (gq < 2) : (gq == 0);
    const int gb = taskb ? blockIdx.x : 0;
    const int mg0 = taskb ? 0 : (blockIdx.x - B) * 4;
    const f32x4 zf = (f32x4){0.f, 0.f, 0.f, 0.f};
    f32x4 rs[2];
    rs[0] = zf; rs[1] = zf;
    // tile 0 x
    f16x8 xb[4];
    {
        const int g0 = taskb ? gb : mg0;
#pragma unroll
        for (int rg = 0; rg < 4; rg++) {
            int row = rg * 16 + r;
            int cl = (row < ROWS) ? row : (ROWS - 1);
            xb[rg] = loader ? *(const f16x8*)(x16 + (g0 * ROWS + cl) * CIN + gq * 8) : z8;
        }
    }
    for (int it = 0; it < 4; it++) {
        const int g = taskb ? gb : (mg0 + it);
        const int rbase = taskb ? (it * 64) : 0;
        f32x4 acc[4][2];
        zacc(acc);
        mm32g(w1, xb, acc);
        epi_cs(acc, b1v, h1s, 136, m0, r, gq, true);
        __syncthreads();
        // prefetch next tile's x: drains at end-of-tile barrier, hidden under GEMM2+accum
        if (it < 3) {
            const int gn = taskb ? gb : (mg0 + it + 1);
            const int rbn = taskb ? ((it + 1) * 64) : 0;
#pragma unroll
            for (int rg = 0; rg < 4; rg++) {
                int row = rbn + rg * 16 + r;
                int cl = (row < ROWS) ? row : (ROWS - 1);
                xb[rg] = loader ? *(const f16x8*)(x16 + (gn * ROWS + cl) * CIN + gq * 8) : z8;
            }
        }
        zacc(acc);
        mm128(w2, h1s, 136, r, gq, acc);
        if (taskb) {
            if (rbase + 64 <= ROWS) {
#pragma unroll
                for (int rg = 0; rg < 4; rg++)
#pragma unroll
                    for (int mi = 0; mi < 2; mi++)
#pragma unroll
                        for (int j = 0; j < 4; j++)
                            rs[mi][j] += fmaxf(acc[rg][mi][j] + b2v[mi][j], 0.f);
            } else {
#pragma unroll
                for (int rg = 0; rg < 4; rg++) {
                    const float mk = ((rbase + rg * 16 + r) < ROWS) ? 1.f : 0.f;
#pragma unroll
                    for (int mi = 0; mi < 2; mi++)
#pragma unroll
                        for (int j = 0; j < 4; j++)
                            rs[mi][j] = fmaf(fmaxf(acc[rg][mi][j] + b2v[mi][j], 0.f), mk, rs[mi][j]);
                }
            }
        } else {
            // machine: per-tile (per-graph) reduce + store
            f32x4 ms[2];
            ms[0] = zf; ms[1] = zf;
#pragma unroll
            for (int rg = 0; rg < 4; rg++) {
                const float mk = ((rg * 16 + r) < ROWS) ? 1.f : 0.f;
#pragma unroll
                for (int mi = 0; mi < 2; mi++)
#pragma unroll
                    for (int j = 0; j < 4; j++)
                        ms[mi][j] = fmaf(fmaxf(acc[rg][mi][j] + b2v[mi][j], 0.f), mk, ms[mi][j]);
            }
#pragma unroll
            for (int mi = 0; mi < 2; mi++)
#pragma unroll
                for (int j = 0; j < 4; j++) {
                    float v = ms[mi][j];
                    v += __shfl_xor(v, 1); v += __shfl_xor(v, 2);
                    v += __shfl_xor(v, 4); v += __shfl_xor(v, 8);
                    ms[mi][j] = v;
                }
            if (r == 0) {
                const float inv = 1.f / (float)M_PER;
#pragma unroll
                for (int mi = 0; mi < 2; mi++) {
                    f32x4 st = ms[mi] * inv;
                    *(f32x4*)(meanM + g * H + (m0 + mi) * 16 + gq * 4) = st;
                }
            }
        }
        if (it < 3) __syncthreads();  // protect h1s before next tile's epi write
    }
    if (taskb) {
#pragma unroll
        for (int mi = 0; mi < 2; mi++)
#pragma unroll
            for (int j = 0; j < 4; j++) {
                float v = rs[mi][j];
                v += __shfl_xor(v, 1); v += __shfl_xor(v, 2);
                v += __shfl_xor(v, 4); v += __shfl_xor(v, 8);
                rs[mi][j] = v;
            }
        if (r == 0) {
            const float inv = 1.f / (float)T_PER;
#pragma unroll
            for (int mi = 0; mi < 2; mi++) {
                f32x4 st = rs[mi] * inv;
                *(f32x4*)(meanT + gb * H + (m0 + mi) * 16 + gq * 4) = st;
            }
        }
    }
}

// ---------------- K4: graph aggr MLP + fused aggr@Wl1b (16 graphs/block) ----------------
__global__ __launch_bounds__(256) void aggr_kernel(const float* __restrict__ meanT, const float* __restrict__ meanM,
        const _Float16* __restrict__ Wa1T, const float* __restrict__ ba1,
        const _Float16* __restrict__ Wa2T, const float* __restrict__ ba2,
        const _Float16* __restrict__ Wl1T, const float* __restrict__ bl1,
        float* __restrict__ agg2) {
    __shared__ __attribute__((aligned(16))) _Float16 cin[16 * 264];
    __shared__ __attribute__((aligned(16))) _Float16 h1s[16 * 136];
    __shared__ __attribute__((aligned(16))) _Float16 ags[16 * 136];
    const int t = threadIdx.x, lane = t & 63, wave = t >> 6;
    const int r = lane & 15, gq = lane >> 4;
    const int m0 = 2 * wave;
    const int g0 = blockIdx.x * 16;
    f16x8 wa1[2][8], wa2[2][4], wl1b[2][4];
#pragma unroll
    for (int mi = 0; mi < 2; mi++)
#pragma unroll
        for (int ks = 0; ks < 8; ks++)
            wa1[mi][ks] = *(const f16x8*)(Wa1T + ((m0 + mi) * 16 + r) * 256 + ks * 32 + gq * 8);
    ld128(wa2, Wa2T, 128, 0, m0, r, gq);
    ld128(wl1b, Wl1T, 384, 128, m0, r, gq);
    f32x4 b1v[2], b2v[2], blv[2];
#pragma unroll
    for (int mi = 0; mi < 2; mi++) {
        b1v[mi] = *(const f32x4*)(ba1 + (m0 + mi) * 16 + gq * 4);
        b2v[mi] = *(const f32x4*)(ba2 + (m0 + mi) * 16 + gq * 4);
        blv[mi] = *(const f32x4*)(bl1 + (m0 + mi) * 16 + gq * 4);
    }
    for (int e = t; e < 16 * 64; e += 256) {
        int j = e >> 6, c4 = e & 63;
        int g = g0 + j;
        float4 v = {0.f, 0.f, 0.f, 0.f};
        if (g < B) v = (c4 < 32) ? *(const float4*)(meanT + g * H + c4 * 4)
                                 : *(const float4*)(meanM + g * H + (c4 - 32) * 4);
        f16x4 hv;
        hv[0] = (_Float16)v.x; hv[1] = (_Float16)v.y; hv[2] = (_Float16)v.z; hv[3] = (_Float16)v.w;
        *(f16x4*)(cin + j * 264 + c4 * 4) = hv;
    }
    __syncthreads();
    f32x4 a0 = {0.f, 0.f, 0.f, 0.f}, a1 = {0.f, 0.f, 0.f, 0.f};
    {
        const _Float16* bp = cin + r * 264 + gq * 8;
#pragma unroll
        for (int ks = 0; ks < 8; ks++) {
            const f16x8 bf = *(const f16x8*)(bp + ks * 32);
            a0 = MFMA16(wa1[0][ks], bf, a0);
            a1 = MFMA16(wa1[1][ks], bf, a1);
        }
    }
    {
        f16x4 h0, h1v;
#pragma unroll
        for (int j = 0; j < 4; j++) {
            h0[j]  = (_Float16)fmaxf(a0[j] + b1v[0][j], 0.f);
            h1v[j] = (_Float16)fmaxf(a1[j] + b1v[1][j], 0.f);
        }
        *(f16x4*)(h1s + r * 136 + m0 * 16 + gq * 4) = h0;
        *(f16x4*)(h1s + r * 136 + (m0 + 1) * 16 + gq * 4) = h1v;
    }
    __syncthreads();
    a0 = (f32x4){0.f, 0.f, 0.f, 0.f}; a1 = (f32x4){0.f, 0.f, 0.f, 0.f};
    {
        const _Float16* bp = h1s + r * 136 + gq * 8;
#pragma unroll
        for (int ks = 0; ks < 4; ks++) {
            const f16x8 bf = *(const f16x8*)(bp + ks * 32);
            a0 = MFMA16(wa2[0][ks], bf, a0);
            a1 = MFMA16(wa2[1][ks], bf, a1);
        }
    }
    {
        f16x4 h0, h1v;
#pragma unroll
        for (int j = 0; j < 4; j++) {
            h0[j]  = (_Float16)(a0[j] + b2v[0][j]);
            h1v[j] = (_Float16)(a1[j] + b2v[1][j]);
        }
        *(f16x4*)(ags + r * 136 + m0 * 16 + gq * 4) = h0;
        *(f16x4*)(ags + r * 136 + (m0 + 1) * 16 + gq * 4) = h1v;
    }
    __syncthreads();
    a0 = (f32x4){0.f, 0.f, 0.f, 0.f}; a1 = (f32x4){0.f, 0.f, 0.f, 0.f};
    {
        const _Float16* bp = ags + r * 136 + gq * 8;
#pragma unroll
        for (int ks = 0; ks < 4; ks++) {
            const f16x8 bf = *(const f16x8*)(bp + ks * 32);
            a0 = MFMA16(wl1b[0][ks], bf, a0);
            a1 = MFMA16(wl1b[1][ks], bf, a1);
        }
    }
    if (g0 + r < B) {
        *(f32x4*)(agg2 + (g0 + r) * H + m0 * 16 + gq * 4) = a0 + blv[0];
        *(f32x4*)(agg2 + (g0 + r) * H + (m0 + 1) * 16 + gq * 4) = a1 + blv[1];
    }
}

// ---------------- K5: label-row head (r6 structure, L2+L3 folded into one W_LO stage) ----------------
__global__ __launch_bounds__(256) void label_kernel(
        const float* __restrict__ xt,
        const _Float16* __restrict__ xt16, const _Float16* __restrict__ xm16,
        const _Float16* __restrict__ Wt1T, const float* __restrict__ bt1f,
        const _Float16* __restrict__ Wt2T, const float* __restrict__ bt2,
        const _Float16* __restrict__ Wm1T, const float* __restrict__ bm1f,
        const _Float16* __restrict__ Wm2T, const float* __restrict__ bm2,
        const _Float16* __restrict__ Wl1T,
        const _Float16* __restrict__ WloT, const float* __restrict__ bfold,
        const float* __restrict__ Wo2, const float* __restrict__ bo2,
        const float* __restrict__ agg2,
        const int* __restrict__ tbatch, const int* __restrict__ lidx,
        float* __restrict__ out) {
    __shared__ __attribute__((aligned(16))) _Float16 xs_t[64 * 40];
    __shared__ __attribute__((aligned(16))) _Float16 xs_m[64 * 40];
    __shared__ __attribute__((aligned(16))) _Float16 h1s[64 * 136];
    __shared__ __attribute__((aligned(16))) _Float16 cat[64 * 264];  // [th | mh]
    __shared__ float psum[4][64];
    __shared__ int ridx[64], gidx[64], midx[64];
    const int t = threadIdx.x;
    const int lane = t & 63, wave = t >> 6;
    const int r = lane & 15, gq = lane >> 4;
    const int m0 = 2 * wave;
    if (t < 64) {
        int i = blockIdx.x * 64 + t;
        int rr = (i < N_LBL) ? lidx[i] : 0;
        ridx[t] = rr;
        int gg = tbatch[rr];
        gidx[t] = gg;
        float tv = xt[rr * 16 + 1];
        midx[t] = (tv == -1.0f) ? -1 : ((int)tv + gg * M_PER);
    }
    __syncthreads();
    f16x4 z4; z4[0] = z4[1] = z4[2] = z4[3] = (_Float16)0.f;
    {
        int j = t >> 2, part = t & 3;
        f16x4 hv = *(const f16x4*)(xt16 + ridx[j] * 16 + part * 4);
        *(f16x4*)(xs_t + j * 40 + part * 4) = hv;
        *(f16x4*)(xs_t + j * 40 + 16 + part * 4) = z4;
    }
    if (t < 128) {
        int j = t >> 1, part = t & 1;
        int m = midx[j];
        f16x4 hv = z4;
        if (m >= 0) hv = *(const f16x4*)(xm16 + m * 8 + part * 4);
        *(f16x4*)(xs_m + j * 40 + part * 4) = hv;
#pragma unroll
        for (int q = 0; q < 3; q++)
            *(f16x4*)(xs_m + j * 40 + 8 + part * 12 + q * 4) = z4;
    }
    __syncthreads();
    f32x4 agg2v[4][2];
#pragma unroll
    for (int rg = 0; rg < 4; rg++)
#pragma unroll
        for (int mi = 0; mi < 2; mi++)
            agg2v[rg][mi] = *(const f32x4*)(agg2 + gidx[rg * 16 + r] * H + (m0 + mi) * 16 + gq * 4);
    f32x4 acc[4][2];
    // --- th ---
    f16x8 wt1[2]; ld32(wt1, Wt1T, m0, r, gq);
    f16x8 wt2[2][4]; ld128(wt2, Wt2T, 128, 0, m0, r, gq);
    f32x4 bva[2], bvb[2];
#pragma unroll
    for (int mi = 0; mi < 2; mi++) {
        bva[mi] = *(const f32x4*)(bt1f + (m0 + mi) * 16 + gq * 4);
        bvb[mi] = *(const f32x4*)(bt2 + (m0 + mi) * 16 + gq * 4);
    }
    zacc(acc);
    mm32(wt1, xs_t, 40, r, gq, acc);
    epi_cs(acc, bva, h1s, 136, m0, r, gq, true);
    f16x8 wm1[2]; ld32(wm1, Wm1T, m0, r, gq);
    __syncthreads();
    zacc(acc);
    mm128(wt2, h1s, 136, r, gq, acc);
    epi_cs(acc, bvb, cat, 264, m0, r, gq, true);
    f16x8 wm2[2][4]; ld128(wm2, Wm2T, 128, 0, m0, r, gq);
    __syncthreads();
    // --- mh ---
#pragma unroll
    for (int mi = 0; mi < 2; mi++) {
        bva[mi] = *(const f32x4*)(bm1f + (m0 + mi) * 16 + gq * 4);
        bvb[mi] = *(const f32x4*)(bm2 + (m0 + mi) * 16 + gq * 4);
    }
    zacc(acc);
    mm32(wm1, xs_m, 40, r, gq, acc);
    epi_cs(acc, bva, h1s, 136, m0, r, gq, true);
    f16x8 wl1a[2][4]; ld128(wl1a, Wl1T, 384, 0, m0, r, gq);
    __syncthreads();
    zacc(acc);
    mm128(wm2, h1s, 136, r, gq, acc);
#pragma unroll
    for (int rg = 0; rg < 4; rg++) {
        const bool sent = (midx[rg * 16 + r] < 0);
#pragma unroll
        for (int mi = 0; mi < 2; mi++) {
            f16x4 hv;
#pragma unroll
            for (int j = 0; j < 4; j++) {
                float v = fmaxf(acc[rg][mi][j] + bvb[mi][j], 0.f);
                hv[j] = (_Float16)(sent ? 0.f : v);
            }
            *(f16x4*)(cat + (rg * 16 + r) * 264 + 128 + (m0 + mi) * 16 + gq * 4) = hv;
        }
    }
    f16x8 wl1c[2][4]; ld128(wl1c, Wl1T, 384, 256, m0, r, gq);
    __syncthreads();
    // --- head L1 (+agg2 epi) ---
    zacc(acc);
    mm128(wl1a, cat, 264, r, gq, acc);
    mm128(wl1c, cat + 128, 264, r, gq, acc);
#pragma unroll
    for (int rg = 0; rg < 4; rg++)
#pragma unroll
        for (int mi = 0; mi < 2; mi++) {
            f16x4 hv;
#pragma unroll
            for (int j = 0; j < 4; j++)
                hv[j] = (_Float16)fmaxf(acc[rg][mi][j] + agg2v[rg][mi][j], 0.f);
            *(f16x4*)(h1s + (rg * 16 + r) * 136 + (m0 + mi) * 16 + gq * 4) = hv;
        }
    f16x8 wlo[2][4]; ld128(wlo, WloT, 128, 0, m0, r, gq);
    __syncthreads();
    // --- head LO (folded L2@Wo1, fp32 bias) + dot Wo2 ---
#pragma unroll
    for (int mi = 0; mi < 2; mi++) bva[mi] = *(const f32x4*)(bfold + (m0 + mi) * 16 + gq * 4);
    f32x4 wo2v[2];
#pragma unroll
    for (int mi = 0; mi < 2; mi++) wo2v[mi] = *(const f32x4*)(Wo2 + (m0 + mi) * 16 + gq * 4);
    zacc(acc);
    mm128(wlo, h1s, 136, r, gq, acc);
#pragma unroll
    for (int rg = 0; rg < 4; rg++) {
        float pv = 0.f;
#pragma unroll
        for (int mi = 0; mi < 2; mi++)
#pragma unroll
            for (int j = 0; j < 4; j++)
                pv += fmaxf(acc[rg][mi][j] + bva[mi][j], 0.f) * wo2v[mi][j];
        pv += __shfl_xor(pv, 16);
        pv += __shfl_xor(pv, 32);
        if (lane < 16) psum[wave][rg * 16 + lane] = pv;
    }
    __syncthreads();
    if (t < 64) {
        int i = blockIdx.x * 64 + t;
        if (i < N_LBL)
            out[i] = psum[0][t] + psum[1][t] + psum[2][t] + psum[3][t] + bo2[0];
    }
}

extern "C" void kernel_launch(void* const* d_in, const int* in_sizes, int n_in,
                              void* d_out, int out_size, void* d_ws, size_t ws_size,
                              hipStream_t stream) {
    const float* xt  = (const float*)d_in[0];
    const float* xm  = (const float*)d_in[1];
    const float* gt  = (const float*)d_in[2];
    const float* btb = (const float*)d_in[3];
    const float* Wt1 = (const float*)d_in[4];  const float* bt1 = (const float*)d_in[5];
    const float* Wt2 = (const float*)d_in[6];  const float* bt2 = (const float*)d_in[7];
    const float* gm  = (const float*)d_in[8];  const float* bmb = (const float*)d_in[9];
    const float* Wm1 = (const float*)d_in[10]; const float* bm1 = (const float*)d_in[11];
    const float* Wm2 = (const float*)d_in[12]; const float* bm2 = (const float*)d_in[13];
    const float* Wa1 = (const float*)d_in[14]; const float* ba1 = (const float*)d_in[15];
    const float* Wa2 = (const float*)d_in[16]; const float* ba2 = (const float*)d_in[17];
    const float* Wl1 = (const float*)d_in[18]; const float* bl1 = (const float*)d_in[19];
    const float* Wl2 = (const float*)d_in[20]; const float* bl2 = (const float*)d_in[21];
    const float* Wo1 = (const float*)d_in[22]; const float* bo1 = (const float*)d_in[23];
    const float* Wo2 = (const float*)d_in[24]; const float* bo2 = (const float*)d_in[25];
    const int* tb  = (const int*)d_in[26];
    const int* lix = (const int*)d_in[28];
    float* wsf = (float*)d_ws;
    _Float16* wh = (_Float16*)(wsf + OFF_HALF);
    _Float16* xt16 = wh + HO_XT16;
    _Float16* xm16 = wh + HO_XM16;
    float* outp = (float*)d_out;

    stats_prep_kernel<<<NB_T + NB_M + NB_P + NB_F, 256, 0, stream>>>(
        xt, xm, xt16, xm16, Wt2, Wm2, Wa1, Wa2, Wl1, Wl2, bl2, Wo1, bo1, wsf, wh);
    finalize_kernel<<<1, 256, 0, stream>>>(gt, btb, gm, bmb, Wt1, bt1, Wm1, bm1, wsf, wh);
    seg_tile4<<<B + 250, 256, 0, stream>>>(xt16, xm16, wh, wsf, bt2, bm2,
                                           wsf + OFF_MEANT, wsf + OFF_MEANM);
    aggr_kernel<<<(B + 15) / 16, 256, 0, stream>>>(wsf + OFF_MEANT, wsf + OFF_MEANM,
                                                   wh + HO_WA1, ba1, wh + HO_WA2, ba2,
                                                   wh + HO_WL1, bl1, wsf + OFF_AGG2);
    label_kernel<<<(N_LBL + 63) / 64, 256, 0, stream>>>(xt, xt16, xm16,
                                                        wh + HO_WT1, wsf + OFF_BT1F, wh + HO_WT2, bt2,
                                                        wh + HO_WM1, wsf + OFF_BM1F, wh + HO_WM2, bm2,
                                                        wh + HO_WL1,
                                                        wh + HO_WLO, wsf + OFF_BFOLD,
                                                        Wo2, bo2,
                                                        wsf + OFF_AGG2, tb, lix, outp);
}

// Round 10
// 61.285 us; speedup vs baseline: 1.4242x; 1.1618x over previous
//
#include <hip/hip_runtime.h>

// Problem constants (fixed by setup_inputs)
constexpr int B     = 1000;
constexpr int T_PER = 250;
constexpr int M_PER = 50;
constexpr int N_T   = B * T_PER;   // 250000
constexpr int N_M   = B * M_PER;   // 50000
constexpr int H     = 128;
constexpr int N_LBL = 25000;
constexpr float EPS = 1e-05f;

constexpr int NB_T = 256;  // bn_stats blocks (tasks)
constexpr int NB_M = 64;   // bn_stats blocks (machines)
constexpr int NB_P = 64;   // prep blocks
constexpr int NB_F = 65;   // fold blocks: 64 x W_LO + 1 x bfold (static, parallel)

// ---- ws layout ----
constexpr int OFF_PART_T = 0;                       // 256 blocks * 32
constexpr int OFF_PART_M = OFF_PART_T + NB_T * 32;  // 64 blocks * 16
constexpr int OFF_AT     = OFF_PART_M + NB_M * 16;  // 16
constexpr int OFF_BT     = OFF_AT + 16;
constexpr int OFF_AM     = OFF_BT + 16;
constexpr int OFF_BM     = OFF_AM + 8;
constexpr int OFF_BT1F   = OFF_BM + 8;              // 128 folded bt1
constexpr int OFF_BM1F   = OFF_BT1F + 128;          // 128 folded bm1
constexpr int OFF_MEANT  = OFF_BM1F + 128;          // B*H task means
constexpr int OFF_MEANM  = OFF_MEANT + B * H;       // B*H machine means
constexpr int OFF_AGG2   = OFF_MEANM + B * H;       // B*H aggr output (Wl1b-folded)
constexpr int OFF_BFOLD  = OFF_AGG2 + B * H;        // 128: bl2@Wo1 + bo1
constexpr int OFF_HALF   = OFF_BFOLD + 128;         // fp16 region (16B aligned)
// fp16 region (half offsets from wh)
constexpr int HO_WT1  = 0;       // 128*32 (prescaled + bias cols 16,17 — written by finalize)
constexpr int HO_WT2  = 4096;    // 128*128
constexpr int HO_WM1  = 20480;   // 128*32 (prescaled + bias cols 8,9)
constexpr int HO_WM2  = 24576;   // 128*128
constexpr int HO_WA1  = 40960;   // 128*256
constexpr int HO_WA2  = 73728;   // 128*128
constexpr int HO_WL1  = 90112;   // 128*384
constexpr int HO_WLO  = 139264;  // 128*128: (Wl2@Wo1) in WT layout — written by stats_prep fold
constexpr int HO_WO1  = 155648;  // 128*128 (slot unused now; offsets kept)
constexpr int HO_XT16 = 172032;             // N_T*16 f16
constexpr int HO_XM16 = HO_XT16 + N_T * 16; // N_M*8 f16

typedef _Float16 f16x8 __attribute__((ext_vector_type(8)));
typedef _Float16 f16x4 __attribute__((ext_vector_type(4)));
typedef float f32x4 __attribute__((ext_vector_type(4)));

#define MFMA16(a, b, c) __builtin_amdgcn_mfma_f32_16x16x32_f16(a, b, c, 0, 0, 0)

// ---------------- column-split MFMA helpers ----------------
__device__ __forceinline__ void zacc(f32x4 acc[4][2]) {
#pragma unroll
    for (int rg = 0; rg < 4; rg++)
#pragma unroll
        for (int mi = 0; mi < 2; mi++) acc[rg][mi] = (f32x4){0.f, 0.f, 0.f, 0.f};
}

__device__ __forceinline__ void ld32(f16x8 w[2], const _Float16* __restrict__ WT,
                                     int m0, int r, int gq) {
#pragma unroll
    for (int mi = 0; mi < 2; mi++)
        w[mi] = *(const f16x8*)(WT + ((m0 + mi) * 16 + r) * 32 + gq * 8);
}

__device__ __forceinline__ void ld128(f16x8 w[2][4], const _Float16* __restrict__ WT,
                                      int lda, int k0, int m0, int r, int gq) {
#pragma unroll
    for (int mi = 0; mi < 2; mi++)
#pragma unroll
        for (int ks = 0; ks < 4; ks++)
            w[mi][ks] = *(const f16x8*)(WT + ((m0 + mi) * 16 + r) * lda + k0 + ks * 32 + gq * 8);
}

// GEMM1 with B-fragments in registers
__device__ __forceinline__ void mm32g(const f16x8 w[2], const f16x8 xb[4], f32x4 acc[4][2]) {
#pragma unroll
    for (int rg = 0; rg < 4; rg++) {
        acc[rg][0] = MFMA16(w[0], xb[rg], acc[rg][0]);
        acc[rg][1] = MFMA16(w[1], xb[rg], acc[rg][1]);
    }
}

__device__ __forceinline__ void mm128(const f16x8 w[2][4], const _Float16* __restrict__ act,
                                      int rstride, int r, int gq, f32x4 acc[4][2]) {
#pragma unroll
    for (int rg = 0; rg < 4; rg++)
#pragma unroll
        for (int ks = 0; ks < 4; ks++) {
            const f16x8 bf = *(const f16x8*)(act + (rg * 16 + r) * rstride + ks * 32 + gq * 8);
            acc[rg][0] = MFMA16(w[0][ks], bf, acc[rg][0]);
            acc[rg][1] = MFMA16(w[1][ks], bf, acc[rg][1]);
        }
}

__device__ __forceinline__ void epi_cs(const f32x4 acc[4][2], const f32x4 bv[2],
                                       _Float16* __restrict__ dst, int dstride,
                                       int m0, int r, int gq, bool relu) {
#pragma unroll
    for (int rg = 0; rg < 4; rg++)
#pragma unroll
        for (int mi = 0; mi < 2; mi++) {
            f16x4 hv;
#pragma unroll
            for (int j = 0; j < 4; j++) {
                float v = acc[rg][mi][j] + bv[mi][j];
                if (relu) v = fmaxf(v, 0.f);
                hv[j] = (_Float16)v;
            }
            *(f16x4*)(dst + (rg * 16 + r) * dstride + (m0 + mi) * 16 + gq * 4) = hv;
        }
}

// ---------------- K1: BN partial stats (float4-vectorized) + x->f16 dump + weight cvt + fold ----------------
// Vectorized: thread covers 4 consecutive elements; flat lane u = t*4+c has column u % C
// (256*4 and NB*256*4 are divisible by C), so per-column partials stay exact.
template <int C, int NB>
__device__ __forceinline__ void stats_body(const float* __restrict__ x,
                                           _Float16* __restrict__ x16, int nelem4,
                                           float* __restrict__ part, int blk, int t,
                                           float* ls, float* lq) {
    float4 s = {0.f, 0.f, 0.f, 0.f}, q = {0.f, 0.f, 0.f, 0.f};
    for (int e = blk * 256 + t; e < nelem4; e += NB * 256) {
        float4 v = *(const float4*)(x + e * 4);
        s.x += v.x; s.y += v.y; s.z += v.z; s.w += v.w;
        q.x += v.x * v.x; q.y += v.y * v.y; q.z += v.z * v.z; q.w += v.w * v.w;
        f16x4 h;
        h[0] = (_Float16)v.x; h[1] = (_Float16)v.y;
        h[2] = (_Float16)v.z; h[3] = (_Float16)v.w;
        *(f16x4*)(x16 + e * 4) = h;
    }
    ls[t * 4 + 0] = s.x; ls[t * 4 + 1] = s.y; ls[t * 4 + 2] = s.z; ls[t * 4 + 3] = s.w;
    lq[t * 4 + 0] = q.x; lq[t * 4 + 1] = q.y; lq[t * 4 + 2] = q.z; lq[t * 4 + 3] = q.w;
    __syncthreads();
    if (t < C) {
        float S = 0.f, Q = 0.f;
        for (int u = t; u < 1024; u += C) { S += ls[u]; Q += lq[u]; }
        part[blk * 2 * C + t] = S;
        part[blk * 2 * C + C + t] = Q;
    }
}

__device__ __forceinline__ void cvt_tr(const float* __restrict__ src, _Float16* __restrict__ dst,
                                       int K, int Kp, int tid, int nt) {
    for (int idx = tid; idx < 128 * Kp; idx += nt) {
        int c = idx / Kp, k = idx - c * Kp;
        float v = (k < K) ? src[k * 128 + c] : 0.f;
        dst[idx] = (_Float16)v;
    }
}

__global__ __launch_bounds__(256) void stats_prep_kernel(
        const float* __restrict__ xt, const float* __restrict__ xm,
        _Float16* __restrict__ xt16, _Float16* __restrict__ xm16,
        const float* __restrict__ Wt2, const float* __restrict__ Wm2,
        const float* __restrict__ Wa1, const float* __restrict__ Wa2,
        const float* __restrict__ Wl1,
        const float* __restrict__ Wl2, const float* __restrict__ bl2,
        const float* __restrict__ Wo1, const float* __restrict__ bo1,
        float* __restrict__ wsf, _Float16* __restrict__ wh) {
    __shared__ float ls[1024], lq[1024];
    const int bid = blockIdx.x, t = threadIdx.x;
    if (bid < NB_T) {
        stats_body<16, NB_T>(xt, xt16, N_T * 16 / 4, wsf + OFF_PART_T, bid, t, ls, lq);
    } else if (bid < NB_T + NB_M) {
        stats_body<8, NB_M>(xm, xm16, N_M * 8 / 4, wsf + OFF_PART_M, bid - NB_T, t, ls, lq);
    } else if (bid < NB_T + NB_M + NB_P) {
        const int tid = (bid - NB_T - NB_M) * 256 + t;
        const int nt = NB_P * 256;
        cvt_tr(Wt2, wh + HO_WT2, 128, 128, tid, nt);
        cvt_tr(Wm2, wh + HO_WM2, 128, 128, tid, nt);
        cvt_tr(Wa1, wh + HO_WA1, 256, 256, tid, nt);
        cvt_tr(Wa2, wh + HO_WA2, 128, 128, tid, nt);
        cvt_tr(Wl1, wh + HO_WL1, 384, 384, tid, nt);
    } else if (bid < NB_T + NB_M + NB_P + 64) {
        // W_LO[k][o] = sum_c f16(Wl2[k][c]) * f16(Wo1[c][o]); stored WT: WloT[o*128+k].
        const int idx = (bid - NB_T - NB_M - NB_P) * 256 + t;  // [0, 16384)
        const int k = idx >> 7, o = idx & 127;
        float s = 0.f;
#pragma unroll 8
        for (int c = 0; c < 128; c++)
            s += (float)(_Float16)Wl2[k * 128 + c] * (float)(_Float16)Wo1[c * 128 + o];
        wh[HO_WLO + o * 128 + k] = (_Float16)s;
    } else {
        // bfold[o] = bo1[o] + sum_c bl2[c]*Wo1[c][o]  (fp32)
        if (t < 128) {
            float s = bo1[t];
#pragma unroll 8
            for (int c = 0; c < 128; c++) s += bl2[c] * Wo1[c * 128 + t];
            wsf[OFF_BFOLD + t] = s;
        }
    }
}

// ---------------- K2: BN finalize + bias folds + prescaled W1T/WM1T (single block, r6 form) ----------------
__global__ __launch_bounds__(256) void finalize_kernel(
        const float* __restrict__ gt, const float* __restrict__ btb,
        const float* __restrict__ gm, const float* __restrict__ bmb,
        const float* __restrict__ Wt1, const float* __restrict__ bt1,
        const float* __restrict__ Wm1, const float* __restrict__ bm1,
        float* __restrict__ ws, _Float16* __restrict__ wh) {
    __shared__ float red[256];
    __shared__ float statT[32], statM[16];
    __shared__ float shT[16], shM[8];
    __shared__ float saT[16], saM[8];
    const int t = threadIdx.x;
    {
        const int slot = t & 31, chunk = t >> 5;
        const float* p = ws + OFF_PART_T;
        float s = 0.f;
        for (int b = chunk * 32; b < chunk * 32 + 32; b++) s += p[b * 32 + slot];
        red[t] = s;
    }
    __syncthreads();
    if (t < 32) {
        float v = 0.f;
#pragma unroll
        for (int c = 0; c < 8; c++) v += red[t + 32 * c];
        statT[t] = v;
    }
    __syncthreads();
    {
        float s = 0.f;
        if (t < 128) {
            const int slot = t & 15, chunk = t >> 4;
            const float* p = ws + OFF_PART_M;
            for (int b = chunk * 8; b < chunk * 8 + 8; b++) s += p[b * 16 + slot];
        }
        red[t] = s;
    }
    __syncthreads();
    if (t < 16) {
        float v = 0.f;
#pragma unroll
        for (int c = 0; c < 8; c++) v += red[t + 16 * c];
        statM[t] = v;
    }
    __syncthreads();
    if (t < 16) {
        float mu  = statT[t] / (float)N_T;
        float var = statT[16 + t] / (float)N_T - mu * mu;
        float a   = gt[t] * rsqrtf(var + EPS);
        ws[OFF_AT + t] = a;
        float b = btb[t] - mu * a;
        ws[OFF_BT + t] = b;
        shT[t] = b;
        saT[t] = a;
    } else if (t < 24) {
        int c = t - 16;
        float mu  = statM[c] / (float)N_M;
        float var = statM[8 + c] / (float)N_M - mu * mu;
        float a   = gm[c] * rsqrtf(var + EPS);
        ws[OFF_AM + c] = a;
        float b = bmb[c] - mu * a;
        ws[OFF_BM + c] = b;
        shM[c] = b;
        saM[c] = a;
    }
    __syncthreads();
    if (t < 128) {
        float s = bt1[t];
#pragma unroll
        for (int k = 0; k < 16; k++) s += shT[k] * Wt1[k * 128 + t];
        ws[OFF_BT1F + t] = s;
        _Float16 row[32];
#pragma unroll
        for (int k = 0; k < 16; k++) row[k] = (_Float16)(Wt1[k * 128 + t] * saT[k]);
        float bh = (float)(_Float16)s;
        row[16] = (_Float16)s;
        row[17] = (_Float16)(s - bh);
#pragma unroll
        for (int k = 18; k < 32; k++) row[k] = (_Float16)0.f;
#pragma unroll
        for (int q = 0; q < 4; q++)
            *(f16x8*)(wh + HO_WT1 + t * 32 + q * 8) = *(const f16x8*)(row + q * 8);
    } else {
        int c = t - 128;
        float s = bm1[c];
#pragma unroll
        for (int k = 0; k < 8; k++) s += shM[k] * Wm1[k * 128 + c];
        ws[OFF_BM1F + c] = s;
        _Float16 row[32];
#pragma unroll
        for (int k = 0; k < 8; k++) row[k] = (_Float16)(Wm1[k * 128 + c] * saM[k]);
        float bh = (float)(_Float16)s;
        row[8] = (_Float16)s;
        row[9] = (_Float16)(s - bh);
#pragma unroll
        for (int k = 10; k < 32; k++) row[k] = (_Float16)0.f;
#pragma unroll
        for (int q = 0; q < 4; q++)
            *(f16x8*)(wh + HO_WM1 + c * 32 + q * 8) = *(const f16x8*)(row + q * 8);
    }
}

// ---------------- K3: seg_tile4 — 1250 blocks x 4 tiles, 17.4KB LDS, weights loaded once ----------------
__global__ __launch_bounds__(256, 3) void seg_tile4(
        const _Float16* __restrict__ xt16, const _Float16* __restrict__ xm16,
        const _Float16* __restrict__ wh, const float* __restrict__ wsf,
        const float* __restrict__ bt2, const float* __restrict__ bm2,
        float* __restrict__ meanT, float* __restrict__ meanM) {
    __shared__ __attribute__((aligned(16))) _Float16 h1s[64 * 136];
    const int t = threadIdx.x, lane = t & 63, w = t >> 6;
    const int r = lane & 15, gq = lane >> 4;
    const int m0 = 2 * w;
    const bool taskb = (blockIdx.x < B);
    const _Float16* W1T = wh + (taskb ? HO_WT1 : HO_WM1);
    const _Float16* W2T = wh + (taskb ? HO_WT2 : HO_WM2);
    const float* b1f = wsf + (taskb ? OFF_BT1F : OFF_BM1F);
    const float* b2  = taskb ? bt2 : bm2;
    const _Float16* x16 = taskb ? xt16 : xm16;
    const int ROWS = taskb ? T_PER : M_PER;
    const int CIN  = taskb ? 16 : 8;
    // --- weight prologue: once per block ---
    f16x8 w1[2]; ld32(w1, W1T, m0, r, gq);
    f16x8 w2[2][4]; ld128(w2, W2T, 128, 0, m0, r, gq);
    f32x4 b1v[2], b2v[2];
#pragma unroll
    for (int mi = 0; mi < 2; mi++) {
        b1v[mi] = *(const f32x4*)(b1f + (m0 + mi) * 16 + gq * 4);
        b2v[mi] = *(const f32x4*)(b2 + (m0 + mi) * 16 + gq * 4);
    }
    f16x8 z8;
#pragma unroll
    for (int e = 0; e < 8; e++) z8[e] = (_Float16)0.f;
    const bool loader = taskb ? (gq < 2) : (gq == 0);
    const int gb = taskb ? blockIdx.x : 0;
    const int mg0 = taskb ? 0 : (blockIdx.x - B) * 4;
    const f32x4 zf = (f32x4){0.f, 0.f, 0.f, 0.f};
    f32x4 rs[2];
    rs[0] = zf; rs[1] = zf;
    // tile 0 x
    f16x8 xb[4];
    {
        const int g0 = taskb ? gb : mg0;
#pragma unroll
        for (int rg = 0; rg < 4; rg++) {
            int row = rg * 16 + r;
            int cl = (row < ROWS) ? row : (ROWS - 1);
            xb[rg] = loader ? *(const f16x8*)(x16 + (g0 * ROWS + cl) * CIN + gq * 8) : z8;
        }
    }
    for (int it = 0; it < 4; it++) {
        const int g = taskb ? gb : (mg0 + it);
        const int rbase = taskb ? (it * 64) : 0;
        f32x4 acc[4][2];
        zacc(acc);
        mm32g(w1, xb, acc);
        epi_cs(acc, b1v, h1s, 136, m0, r, gq, true);
        __syncthreads();
        // prefetch next tile's x: drains at end-of-tile barrier, hidden under GEMM2+accum
        if (it < 3) {
            const int gn = taskb ? gb : (mg0 + it + 1);
            const int rbn = taskb ? ((it + 1) * 64) : 0;
#pragma unroll
            for (int rg = 0; rg < 4; rg++) {
                int row = rbn + rg * 16 + r;
                int cl = (row < ROWS) ? row : (ROWS - 1);
                xb[rg] = loader ? *(const f16x8*)(x16 + (gn * ROWS + cl) * CIN + gq * 8) : z8;
            }
        }
        zacc(acc);
        mm128(w2, h1s, 136, r, gq, acc);
        if (taskb) {
            if (rbase + 64 <= ROWS) {
#pragma unroll
                for (int rg = 0; rg < 4; rg++)
#pragma unroll
                    for (int mi = 0; mi < 2; mi++)
#pragma unroll
                        for (int j = 0; j < 4; j++)
                            rs[mi][j] += fmaxf(acc[rg][mi][j] + b2v[mi][j], 0.f);
            } else {
#pragma unroll
                for (int rg = 0; rg < 4; rg++) {
                    const float mk = ((rbase + rg * 16 + r) < ROWS) ? 1.f : 0.f;
#pragma unroll
                    for (int mi = 0; mi < 2; mi++)
#pragma unroll
                        for (int j = 0; j < 4; j++)
                            rs[mi][j] = fmaf(fmaxf(acc[rg][mi][j] + b2v[mi][j], 0.f), mk, rs[mi][j]);
                }
            }
        } else {
            // machine: per-tile (per-graph) reduce + store
            f32x4 ms[2];
            ms[0] = zf; ms[1] = zf;
#pragma unroll
            for (int rg = 0; rg < 4; rg++) {
                const float mk = ((rg * 16 + r) < ROWS) ? 1.f : 0.f;
#pragma unroll
                for (int mi = 0; mi < 2; mi++)
#pragma unroll
                    for (int j = 0; j < 4; j++)
                        ms[mi][j] = fmaf(fmaxf(acc[rg][mi][j] + b2v[mi][j], 0.f), mk, ms[mi][j]);
            }
#pragma unroll
            for (int mi = 0; mi < 2; mi++)
#pragma unroll
                for (int j = 0; j < 4; j++) {
                    float v = ms[mi][j];
                    v += __shfl_xor(v, 1); v += __shfl_xor(v, 2);
                    v += __shfl_xor(v, 4); v += __shfl_xor(v, 8);
                    ms[mi][j] = v;
                }
            if (r == 0) {
                const float inv = 1.f / (float)M_PER;
#pragma unroll
                for (int mi = 0; mi < 2; mi++) {
                    f32x4 st = ms[mi] * inv;
                    *(f32x4*)(meanM + g * H + (m0 + mi) * 16 + gq * 4) = st;
                }
            }
        }
        if (it < 3) __syncthreads();  // protect h1s before next tile's epi write
    }
    if (taskb) {
#pragma unroll
        for (int mi = 0; mi < 2; mi++)
#pragma unroll
            for (int j = 0; j < 4; j++) {
                float v = rs[mi][j];
                v += __shfl_xor(v, 1); v += __shfl_xor(v, 2);
                v += __shfl_xor(v, 4); v += __shfl_xor(v, 8);
                rs[mi][j] = v;
            }
        if (r == 0) {
            const float inv = 1.f / (float)T_PER;
#pragma unroll
            for (int mi = 0; mi < 2; mi++) {
                f32x4 st = rs[mi] * inv;
                *(f32x4*)(meanT + gb * H + (m0 + mi) * 16 + gq * 4) = st;
            }
        }
    }
}

// ---------------- K4: graph aggr MLP + fused aggr@Wl1b (16 graphs/block) ----------------
__global__ __launch_bounds__(256) void aggr_kernel(const float* __restrict__ meanT, const float* __restrict__ meanM,
        const _Float16* __restrict__ Wa1T, const float* __restrict__ ba1,
        const _Float16* __restrict__ Wa2T, const float* __restrict__ ba2,
        const _Float16* __restrict__ Wl1T, const float* __restrict__ bl1,
        float* __restrict__ agg2) {
    __shared__ __attribute__((aligned(16))) _Float16 cin[16 * 264];
    __shared__ __attribute__((aligned(16))) _Float16 h1s[16 * 136];
    __shared__ __attribute__((aligned(16))) _Float16 ags[16 * 136];
    const int t = threadIdx.x, lane = t & 63, wave = t >> 6;
    const int r = lane & 15, gq = lane >> 4;
    const int m0 = 2 * wave;
    const int g0 = blockIdx.x * 16;
    f16x8 wa1[2][8], wa2[2][4], wl1b[2][4];
#pragma unroll
    for (int mi = 0; mi < 2; mi++)
#pragma unroll
        for (int ks = 0; ks < 8; ks++)
            wa1[mi][ks] = *(const f16x8*)(Wa1T + ((m0 + mi) * 16 + r) * 256 + ks * 32 + gq * 8);
    ld128(wa2, Wa2T, 128, 0, m0, r, gq);
    ld128(wl1b, Wl1T, 384, 128, m0, r, gq);
    f32x4 b1v[2], b2v[2], blv[2];
#pragma unroll
    for (int mi = 0; mi < 2; mi++) {
        b1v[mi] = *(const f32x4*)(ba1 + (m0 + mi) * 16 + gq * 4);
        b2v[mi] = *(const f32x4*)(ba2 + (m0 + mi) * 16 + gq * 4);
        blv[mi] = *(const f32x4*)(bl1 + (m0 + mi) * 16 + gq * 4);
    }
    for (int e = t; e < 16 * 64; e += 256) {
        int j = e >> 6, c4 = e & 63;
        int g = g0 + j;
        float4 v = {0.f, 0.f, 0.f, 0.f};
        if (g < B) v = (c4 < 32) ? *(const float4*)(meanT + g * H + c4 * 4)
                                 : *(const float4*)(meanM + g * H + (c4 - 32) * 4);
        f16x4 hv;
        hv[0] = (_Float16)v.x; hv[1] = (_Float16)v.y; hv[2] = (_Float16)v.z; hv[3] = (_Float16)v.w;
        *(f16x4*)(cin + j * 264 + c4 * 4) = hv;
    }
    __syncthreads();
    f32x4 a0 = {0.f, 0.f, 0.f, 0.f}, a1 = {0.f, 0.f, 0.f, 0.f};
    {
        const _Float16* bp = cin + r * 264 + gq * 8;
#pragma unroll
        for (int ks = 0; ks < 8; ks++) {
            const f16x8 bf = *(const f16x8*)(bp + ks * 32);
            a0 = MFMA16(wa1[0][ks], bf, a0);
            a1 = MFMA16(wa1[1][ks], bf, a1);
        }
    }
    {
        f16x4 h0, h1v;
#pragma unroll
        for (int j = 0; j < 4; j++) {
            h0[j]  = (_Float16)fmaxf(a0[j] + b1v[0][j], 0.f);
            h1v[j] = (_Float16)fmaxf(a1[j] + b1v[1][j], 0.f);
        }
        *(f16x4*)(h1s + r * 136 + m0 * 16 + gq * 4) = h0;
        *(f16x4*)(h1s + r * 136 + (m0 + 1) * 16 + gq * 4) = h1v;
    }
    __syncthreads();
    a0 = (f32x4){0.f, 0.f, 0.f, 0.f}; a1 = (f32x4){0.f, 0.f, 0.f, 0.f};
    {
        const _Float16* bp = h1s + r * 136 + gq * 8;
#pragma unroll
        for (int ks = 0; ks < 4; ks++) {
            const f16x8 bf = *(const f16x8*)(bp + ks * 32);
            a0 = MFMA16(wa2[0][ks], bf, a0);
            a1 = MFMA16(wa2[1][ks], bf, a1);
        }
    }
    {
        f16x4 h0, h1v;
#pragma unroll
        for (int j = 0; j < 4; j++) {
            h0[j]  = (_Float16)(a0[j] + b2v[0][j]);
            h1v[j] = (_Float16)(a1[j] + b2v[1][j]);
        }
        *(f16x4*)(ags + r * 136 + m0 * 16 + gq * 4) = h0;
        *(f16x4*)(ags + r * 136 + (m0 + 1) * 16 + gq * 4) = h1v;
    }
    __syncthreads();
    a0 = (f32x4){0.f, 0.f, 0.f, 0.f}; a1 = (f32x4){0.f, 0.f, 0.f, 0.f};
    {
        const _Float16* bp = ags + r * 136 + gq * 8;
#pragma unroll
        for (int ks = 0; ks < 4; ks++) {
            const f16x8 bf = *(const f16x8*)(bp + ks * 32);
            a0 = MFMA16(wl1b[0][ks], bf, a0);
            a1 = MFMA16(wl1b[1][ks], bf, a1);
        }
    }
    if (g0 + r < B) {
        *(f32x4*)(agg2 + (g0 + r) * H + m0 * 16 + gq * 4) = a0 + blv[0];
        *(f32x4*)(agg2 + (g0 + r) * H + (m0 + 1) * 16 + gq * 4) = a1 + blv[1];
    }
}

// ---------------- K5: label-row head — 6 stages, direct-global B-frags (no xs LDS), 3 blocks/CU ----------------
__global__ __launch_bounds__(256, 3) void label_kernel(
        const float* __restrict__ xt,
        const _Float16* __restrict__ xt16, const _Float16* __restrict__ xm16,
        const _Float16* __restrict__ Wt1T, const float* __restrict__ bt1f,
        const _Float16* __restrict__ Wt2T, const float* __restrict__ bt2,
        const _Float16* __restrict__ Wm1T, const float* __restrict__ bm1f,
        const _Float16* __restrict__ Wm2T, const float* __restrict__ bm2,
        const _Float16* __restrict__ Wl1T,
        const _Float16* __restrict__ WloT, const float* __restrict__ bfold,
        const float* __restrict__ Wo2, const float* __restrict__ bo2,
        const float* __restrict__ agg2,
        const int* __restrict__ tbatch, const int* __restrict__ lidx,
        float* __restrict__ out) {
    __shared__ __attribute__((aligned(16))) _Float16 h1s[64 * 136];
    __shared__ __attribute__((aligned(16))) _Float16 cat[64 * 264];  // [th | mh]
    __shared__ float psum[4][64];
    __shared__ int ridx[64], gidx[64], midx[64];
    const int t = threadIdx.x;
    const int lane = t & 63, wave = t >> 6;
    const int r = lane & 15, gq = lane >> 4;
    const int m0 = 2 * wave;
    if (t < 64) {
        int i = blockIdx.x * 64 + t;
        int rr = (i < N_LBL) ? lidx[i] : 0;
        ridx[t] = rr;
        int gg = tbatch[rr];
        gidx[t] = gg;
        float tv = xt[rr * 16 + 1];
        midx[t] = (tv == -1.0f) ? -1 : ((int)tv + gg * M_PER);
    }
    __syncthreads();
    f16x8 z8;
#pragma unroll
    for (int e = 0; e < 8; e++) z8[e] = (_Float16)0.f;
    // B-fragments for both GEMM1s straight from global f16 x (r2-proven pattern)
    f16x8 xbT[4], xbM[4];
#pragma unroll
    for (int rg = 0; rg < 4; rg++) {
        int rr = ridx[rg * 16 + r];
        xbT[rg] = (gq < 2) ? *(const f16x8*)(xt16 + rr * 16 + gq * 8) : z8;
        int mm = midx[rg * 16 + r];
        xbM[rg] = (gq == 0 && mm >= 0) ? *(const f16x8*)(xm16 + mm * 8) : z8;
    }
    f32x4 agg2v[4][2];
#pragma unroll
    for (int rg = 0; rg < 4; rg++)
#pragma unroll
        for (int mi = 0; mi < 2; mi++)
            agg2v[rg][mi] = *(const f32x4*)(agg2 + gidx[rg * 16 + r] * H + (m0 + mi) * 16 + gq * 4);
    f32x4 acc[4][2];
    // --- th1 ---
    f16x8 wt1[2]; ld32(wt1, Wt1T, m0, r, gq);
    f16x8 wt2[2][4]; ld128(wt2, Wt2T, 128, 0, m0, r, gq);
    f32x4 bva[2], bvb[2];
#pragma unroll
    for (int mi = 0; mi < 2; mi++) {
        bva[mi] = *(const f32x4*)(bt1f + (m0 + mi) * 16 + gq * 4);
        bvb[mi] = *(const f32x4*)(bt2 + (m0 + mi) * 16 + gq * 4);
    }
    zacc(acc);
    mm32g(wt1, xbT, acc);
    epi_cs(acc, bva, h1s, 136, m0, r, gq, true);
    f16x8 wm1[2]; ld32(wm1, Wm1T, m0, r, gq);
    __syncthreads();
    // --- th2 -> cat[th] ---
    zacc(acc);
    mm128(wt2, h1s, 136, r, gq, acc);
    epi_cs(acc, bvb, cat, 264, m0, r, gq, true);
    f16x8 wm2[2][4]; ld128(wm2, Wm2T, 128, 0, m0, r, gq);
    __syncthreads();
    // --- mh1 ---
#pragma unroll
    for (int mi = 0; mi < 2; mi++) {
        bva[mi] = *(const f32x4*)(bm1f + (m0 + mi) * 16 + gq * 4);
        bvb[mi] = *(const f32x4*)(bm2 + (m0 + mi) * 16 + gq * 4);
    }
    zacc(acc);
    mm32g(wm1, xbM, acc);
    epi_cs(acc, bva, h1s, 136, m0, r, gq, true);
    f16x8 wl1a[2][4]; ld128(wl1a, Wl1T, 384, 0, m0, r, gq);
    __syncthreads();
    // --- mh2 -> cat[mh] (sentinel-masked) ---
    zacc(acc);
    mm128(wm2, h1s, 136, r, gq, acc);
#pragma unroll
    for (int rg = 0; rg < 4; rg++) {
        const bool sent = (midx[rg * 16 + r] < 0);
#pragma unroll
        for (int mi = 0; mi < 2; mi++) {
            f16x4 hv;
#pragma unroll
            for (int j = 0; j < 4; j++) {
                float v = fmaxf(acc[rg][mi][j] + bvb[mi][j], 0.f);
                hv[j] = (_Float16)(sent ? 0.f : v);
            }
            *(f16x4*)(cat + (rg * 16 + r) * 264 + 128 + (m0 + mi) * 16 + gq * 4) = hv;
        }
    }
    f16x8 wl1c[2][4]; ld128(wl1c, Wl1T, 384, 256, m0, r, gq);
    __syncthreads();
    // --- head L1 (+agg2 epi) ---
    zacc(acc);
    mm128(wl1a, cat, 264, r, gq, acc);
    mm128(wl1c, cat + 128, 264, r, gq, acc);
#pragma unroll
    for (int rg = 0; rg < 4; rg++)
#pragma unroll
        for (int mi = 0; mi < 2; mi++) {
            f16x4 hv;
#pragma unroll
            for (int j = 0; j < 4; j++)
                hv[j] = (_Float16)fmaxf(acc[rg][mi][j] + agg2v[rg][mi][j], 0.f);
            *(f16x4*)(h1s + (rg * 16 + r) * 136 + (m0 + mi) * 16 + gq * 4) = hv;
        }
    f16x8 wlo[2][4]; ld128(wlo, WloT, 128, 0, m0, r, gq);
    __syncthreads();
    // --- head LO (folded L2@Wo1, fp32 bias) + dot Wo2 ---
#pragma unroll
    for (int mi = 0; mi < 2; mi++) bva[mi] = *(const f32x4*)(bfold + (m0 + mi) * 16 + gq * 4);
    f32x4 wo2v[2];
#pragma unroll
    for (int mi = 0; mi < 2; mi++) wo2v[mi] = *(const f32x4*)(Wo2 + (m0 + mi) * 16 + gq * 4);
    zacc(acc);
    mm128(wlo, h1s, 136, r, gq, acc);
#pragma unroll
    for (int rg = 0; rg < 4; rg++) {
        float pv = 0.f;
#pragma unroll
        for (int mi = 0; mi < 2; mi++)
#pragma unroll
            for (int j = 0; j < 4; j++)
                pv += fmaxf(acc[rg][mi][j] + bva[mi][j], 0.f) * wo2v[mi][j];
        pv += __shfl_xor(pv, 16);
        pv += __shfl_xor(pv, 32);
        if (lane < 16) psum[wave][rg * 16 + lane] = pv;
    }
    __syncthreads();
    if (t < 64) {
        int i = blockIdx.x * 64 + t;
        if (i < N_LBL)
            out[i] = psum[0][t] + psum[1][t] + psum[2][t] + psum[3][t] + bo2[0];
    }
}

extern "C" void kernel_launch(void* const* d_in, const int* in_sizes, int n_in,
                              void* d_out, int out_size, void* d_ws, size_t ws_size,
                              hipStream_t stream) {
    const float* xt  = (const float*)d_in[0];
    const float* xm  = (const float*)d_in[1];
    const float* gt  = (const float*)d_in[2];
    const float* btb = (const float*)d_in[3];
    const float* Wt1 = (const float*)d_in[4];  const float* bt1 = (const float*)d_in[5];
    const float* Wt2 = (const float*)d_in[6];  const float* bt2 = (const float*)d_in[7];
    const float* gm  = (const float*)d_in[8];  const float* bmb = (const float*)d_in[9];
    const float* Wm1 = (const float*)d_in[10]; const float* bm1 = (const float*)d_in[11];
    const float* Wm2 = (const float*)d_in[12]; const float* bm2 = (const float*)d_in[13];
    const float* Wa1 = (const float*)d_in[14]; const float* ba1 = (const float*)d_in[15];
    const float* Wa2 = (const float*)d_in[16]; const float* ba2 = (const float*)d_in[17];
    const float* Wl1 = (const float*)d_in[18]; const float* bl1 = (const float*)d_in[19];
    const float* Wl2 = (const float*)d_in[20]; const float* bl2 = (const float*)d_in[21];
    const float* Wo1 = (const float*)d_in[22]; const float* bo1 = (const float*)d_in[23];
    const float* Wo2 = (const float*)d_in[24]; const float* bo2 = (const float*)d_in[25];
    const int* tb  = (const int*)d_in[26];
    const int* lix = (const int*)d_in[28];
    float* wsf = (float*)d_ws;
    _Float16* wh = (_Float16*)(wsf + OFF_HALF);
    _Float16* xt16 = wh + HO_XT16;
    _Float16* xm16 = wh + HO_XM16;
    float* outp = (float*)d_out;

    stats_prep_kernel<<<NB_T + NB_M + NB_P + NB_F, 256, 0, stream>>>(
        xt, xm, xt16, xm16, Wt2, Wm2, Wa1, Wa2, Wl1, Wl2, bl2, Wo1, bo1, wsf, wh);
    finalize_kernel<<<1, 256, 0, stream>>>(gt, btb, gm, bmb, Wt1, bt1, Wm1, bm1, wsf, wh);
    seg_tile4<<<B + 250, 256, 0, stream>>>(xt16, xm16, wh, wsf, bt2, bm2,
                                           wsf + OFF_MEANT, wsf + OFF_MEANM);
    aggr_kernel<<<(B + 15) / 16, 256, 0, stream>>>(wsf + OFF_MEANT, wsf + OFF_MEANM,
                                                   wh + HO_WA1, ba1, wh + HO_WA2, ba2,
                                                   wh + HO_WL1, bl1, wsf + OFF_AGG2);
    label_kernel<<<(N_LBL + 63) / 64, 256, 0, stream>>>(xt, xt16, xm16,
                                                        wh + HO_WT1, wsf + OFF_BT1F, wh + HO_WT2, bt2,
                                                        wh + HO_WM1, wsf + OFF_BM1F, wh + HO_WM2, bm2,
                                                        wh + HO_WL1,
                                                        wh + HO_WLO, wsf + OFF_BFOLD,
                                                        Wo2, bo2,
                                                        wsf + OFF_AGG2, tb, lix, outp);
}